// Round 1
// baseline (1147.835 us; speedup 1.0000x reference)
//
#include <hip/hip_runtime.h>
#include <hip/hip_bf16.h>

#define TSTEPS 28
#define BDIM 2048
#define DDIM 1024

typedef __attribute__((ext_vector_type(8))) short bf16x8;
typedef __attribute__((ext_vector_type(4))) float f32x4;
typedef __hip_bfloat16 bf16;

__device__ __forceinline__ unsigned short f2b(float f) {
  bf16 h = __float2bfloat16(f);
  return *reinterpret_cast<unsigned short*>(&h);
}
__device__ __forceinline__ float b2f(bf16 h) { return __bfloat162float(h); }

__device__ __forceinline__ void gload16(const void* g, void* l) {
  __builtin_amdgcn_global_load_lds(
      (const __attribute__((address_space(1))) void*)g,
      (__attribute__((address_space(3))) void*)l, 16, 0, 0);
}

// ---------------- f32 -> bf16 convert (vectorized) ----------------
typedef __attribute__((ext_vector_type(4))) unsigned short u16x4;
__global__ void conv_kernel(const float* __restrict__ in, unsigned short* __restrict__ out, int n4) {
  int i = blockIdx.x * blockDim.x + threadIdx.x;
  const int stride = gridDim.x * blockDim.x;
  for (; i < n4; i += stride) {
    const float4 v = *(const float4*)&in[(size_t)i * 4];
    u16x4 o;
    o.x = f2b(v.x); o.y = f2b(v.y); o.z = f2b(v.z); o.w = f2b(v.w);
    *(u16x4*)&out[(size_t)i * 4] = o;
  }
}

// ---------------- generic C = A*W^T + bias (f32 out) ----------------
// A: [M][K] bf16, W: [N][K] bf16, out: [M][Ntot] f32. BM=128 BN=64 BK=32.
template <int K>
__global__ __launch_bounds__(256, 2) void gemm_bias_kernel(
    const bf16* __restrict__ A, const bf16* __restrict__ W,
    const float* __restrict__ bias, float* __restrict__ out, int Ntot) {
  constexpr int NT = K / 32;
  __shared__ __align__(16) bf16 lds[2][6144];  // A 128x32 (4096) + B 64x32 (2048)
  const int tid = threadIdx.x;
  const int lane = tid & 63;
  const int l15 = lane & 15, l4 = lane >> 4;
  const int wid = tid >> 6, wm = wid >> 1, wn = wid & 1;
  const int m0 = blockIdx.x * 128, n0 = blockIdx.y * 64;
  const int ra = tid >> 2, cb = (tid & 3) * 8;

  f32x4 acc[4][2] = {};

  auto STAGE = [&](int buf, int kt) {
    const int k0 = kt * 32;
    gload16(&A[(size_t)(m0 + ra) * K + k0 + cb], &lds[buf][tid * 8]);
    gload16(&A[(size_t)(m0 + 64 + ra) * K + k0 + cb], &lds[buf][2048 + tid * 8]);
    gload16(&W[(size_t)(n0 + ra) * K + k0 + cb], &lds[buf][4096 + tid * 8]);
  };

  STAGE(0, 0);
  __syncthreads();
  for (int kt = 0; kt < NT; ++kt) {
    const int buf = kt & 1;
    if (kt + 1 < NT) STAGE(buf ^ 1, kt + 1);
    bf16x8 af[4], bfr[2];
#pragma unroll
    for (int m = 0; m < 4; ++m)
      af[m] = *(const bf16x8*)&lds[buf][(wm * 64 + m * 16 + l15) * 32 + l4 * 8];
#pragma unroll
    for (int n = 0; n < 2; ++n)
      bfr[n] = *(const bf16x8*)&lds[buf][4096 + (wn * 32 + n * 16 + l15) * 32 + l4 * 8];
#pragma unroll
    for (int m = 0; m < 4; ++m)
#pragma unroll
      for (int n = 0; n < 2; ++n)
        acc[m][n] = __builtin_amdgcn_mfma_f32_16x16x32_bf16(af[m], bfr[n], acc[m][n], 0, 0, 0);
    __syncthreads();
  }

#pragma unroll
  for (int m = 0; m < 4; ++m) {
#pragma unroll
    for (int n = 0; n < 2; ++n) {
      const int col = n0 + wn * 32 + n * 16 + l15;
      const int rowb = m0 + wm * 64 + m * 16 + l4 * 4;
      const float bv = bias[col];
#pragma unroll
      for (int r = 0; r < 4; ++r)
        out[(size_t)(rowb + r) * Ntot + col] = acc[m][n][r] + bv;
    }
  }
}

// ---------------- row LayerNorm: xraw[2048][1024] f32 -> h0 bf16 ----------------
__global__ __launch_bounds__(256) void ln_kernel(const float* __restrict__ x,
                                                 const float* __restrict__ w,
                                                 const float* __restrict__ b,
                                                 bf16* __restrict__ h0) {
  const int row = blockIdx.x, tid = threadIdx.x;
  const float4 v = *(const float4*)&x[(size_t)row * 1024 + tid * 4];
  float vv[4] = {v.x, v.y, v.z, v.w};
  float s = vv[0] + vv[1] + vv[2] + vv[3];
  float sq = vv[0] * vv[0] + vv[1] * vv[1] + vv[2] * vv[2] + vv[3] * vv[3];
#pragma unroll
  for (int off = 32; off; off >>= 1) {
    s += __shfl_down(s, off);
    sq += __shfl_down(sq, off);
  }
  __shared__ float sa[4], sb[4];
  const int lane = tid & 63, wid = tid >> 6;
  if (lane == 0) { sa[wid] = s; sb[wid] = sq; }
  __syncthreads();
  s = sa[0] + sa[1] + sa[2] + sa[3];
  sq = sb[0] + sb[1] + sb[2] + sb[3];
  const float mu = s * (1.f / 1024.f);
  const float var = sq * (1.f / 1024.f) - mu * mu;
  const float rs = rsqrtf(var + 1e-5f);
  bf16* o = &h0[(size_t)row * 1024];
#pragma unroll
  for (int j = 0; j < 4; ++j) {
    const int c = tid * 4 + j;
    o[c] = __float2bfloat16((vv[j] - mu) * rs * w[c] + b[c]);
  }
}

// ---------------- fused GRU step: gh = h_in @ w_hh^T, gates, h_new ----------------
// grid (16,16): block computes 128 rows x 64 cols of h_new (3 gate GEMMs fused).
__global__ __launch_bounds__(256, 1) void gru_step_kernel(
    const bf16* __restrict__ hin, bf16* __restrict__ hout,
    const float* __restrict__ trueinp, const int* __restrict__ tfmask,
    const bf16* __restrict__ whh, const float* __restrict__ bhh,
    const float* __restrict__ gi, float* __restrict__ out, int tstep) {
  __shared__ __align__(16) bf16 lds[2][4096 + 3 * 2048];  // A 128x32 + 3x B 64x32
  const int tid = threadIdx.x;
  const int lane = tid & 63;
  const int l15 = lane & 15, l4 = lane >> 4;
  const int wid = tid >> 6, wm = wid >> 1, wn = wid & 1;
  const int m0 = blockIdx.x * 128, n0 = blockIdx.y * 64;
  const int ra = tid >> 2, cb = (tid & 3) * 8;
  const bool mask = tfmask[tstep] != 0;

  f32x4 acc[3][4][2] = {};

  auto STAGE = [&](int buf, int kt) {
    const int k0 = kt * 32;
    if (!mask) {
      gload16(&hin[(size_t)(m0 + ra) * 1024 + k0 + cb], &lds[buf][tid * 8]);
      gload16(&hin[(size_t)(m0 + 64 + ra) * 1024 + k0 + cb], &lds[buf][2048 + tid * 8]);
    } else {
      const int km = (k0 & 255) + cb;
#pragma unroll
      for (int i = 0; i < 2; ++i) {
        const int row = m0 + i * 64 + ra;
        const float* src = &trueinp[((size_t)row * TSTEPS + tstep) * 256 + km];
        const float4 v0 = *(const float4*)src;
        const float4 v1 = *(const float4*)(src + 4);
        const float a0[8] = {v0.x, v0.y, v0.z, v0.w, v1.x, v1.y, v1.z, v1.w};
        bf16x8 sv;
#pragma unroll
        for (int j = 0; j < 8; ++j) sv[j] = (short)f2b(a0[j]);
        *(bf16x8*)&lds[buf][i * 2048 + tid * 8] = sv;
      }
    }
#pragma unroll
    for (int g = 0; g < 3; ++g)
      gload16(&whh[(size_t)(g * 1024 + n0 + ra) * 1024 + k0 + cb],
              &lds[buf][4096 + g * 2048 + tid * 8]);
  };

  STAGE(0, 0);
  __syncthreads();
  for (int kt = 0; kt < 32; ++kt) {
    const int buf = kt & 1;
    if (kt + 1 < 32) STAGE(buf ^ 1, kt + 1);
    bf16x8 af[4], bfr[3][2];
#pragma unroll
    for (int m = 0; m < 4; ++m)
      af[m] = *(const bf16x8*)&lds[buf][(wm * 64 + m * 16 + l15) * 32 + l4 * 8];
#pragma unroll
    for (int g = 0; g < 3; ++g)
#pragma unroll
      for (int n = 0; n < 2; ++n)
        bfr[g][n] = *(const bf16x8*)&lds[buf][4096 + g * 2048 + (wn * 32 + n * 16 + l15) * 32 + l4 * 8];
#pragma unroll
    for (int g = 0; g < 3; ++g)
#pragma unroll
      for (int m = 0; m < 4; ++m)
#pragma unroll
        for (int n = 0; n < 2; ++n)
          acc[g][m][n] = __builtin_amdgcn_mfma_f32_16x16x32_bf16(af[m], bfr[g][n], acc[g][m][n], 0, 0, 0);
    __syncthreads();
  }

  float* outT = out + (size_t)tstep * BDIM * DDIM;
#pragma unroll
  for (int m = 0; m < 4; ++m) {
#pragma unroll
    for (int n = 0; n < 2; ++n) {
      const int col = n0 + wn * 32 + n * 16 + l15;
      const int rowb = m0 + wm * 64 + m * 16 + l4 * 4;
      const float br = bhh[col], bz = bhh[col + 1024], bn = bhh[col + 2048];
#pragma unroll
      for (int r = 0; r < 4; ++r) {
        const int row = rowb + r;
        const float* girow = &gi[(size_t)row * 3072];
        const float ir = girow[col], iz = girow[col + 1024], inn = girow[col + 2048];
        const float hr = acc[0][m][n][r] + br;
        const float hz = acc[1][m][n][r] + bz;
        const float hn = acc[2][m][n][r] + bn;
        const float hinv = mask ? trueinp[((size_t)row * TSTEPS + tstep) * 256 + (col & 255)]
                                : b2f(hin[(size_t)row * 1024 + col]);
        const float rg = 1.f / (1.f + __expf(-(ir + hr)));
        const float ug = 1.f / (1.f + __expf(-(iz + hz)));
        const float e2 = __expf(2.f * (inn + rg * hn));
        const float ng = 1.f - 2.f / (e2 + 1.f);  // tanh
        const float hnew = (1.f - ug) * ng + ug * hinv;
        outT[(size_t)row * 1024 + col] = hnew;
        hout[(size_t)row * 1024 + col] = __float2bfloat16(hnew);
      }
    }
  }
}

extern "C" void kernel_launch(void* const* d_in, const int* in_sizes, int n_in,
                              void* d_out, int out_size, void* d_ws, size_t ws_size,
                              hipStream_t stream) {
  (void)in_sizes; (void)n_in; (void)out_size; (void)ws_size;
  const float* z = (const float*)d_in[0];
  const float* trueinp = (const float*)d_in[1];
  const int* tfmask = (const int*)d_in[2];
  const float* fc_w = (const float*)d_in[3];
  const float* fc_b = (const float*)d_in[4];
  const float* ln_w = (const float*)d_in[5];
  const float* ln_b = (const float*)d_in[6];
  const float* w_ih = (const float*)d_in[7];
  const float* b_ih = (const float*)d_in[8];
  const float* w_hh = (const float*)d_in[9];
  const float* b_hh = (const float*)d_in[10];
  float* out = (float*)d_out;

  char* ws = (char*)d_ws;
  size_t o = 0;
  float* xraw = (float*)(ws + o); o += (size_t)2048 * 1024 * 4;
  float* gi   = (float*)(ws + o); o += (size_t)2048 * 3072 * 4;
  bf16* h0    = (bf16*)(ws + o);  o += (size_t)2048 * 1024 * 2;
  bf16* h1    = (bf16*)(ws + o);  o += (size_t)2048 * 1024 * 2;
  bf16* zb    = (bf16*)(ws + o);  o += (size_t)2048 * 256 * 2;
  bf16* fcwb  = (bf16*)(ws + o);  o += (size_t)1024 * 256 * 2;
  bf16* wihb  = (bf16*)(ws + o);  o += (size_t)3072 * 1024 * 2;
  bf16* whhb  = (bf16*)(ws + o);  o += (size_t)3072 * 1024 * 2;

  conv_kernel<<<1024, 256, 0, stream>>>(z, (unsigned short*)zb, 2048 * 256 / 4);
  conv_kernel<<<512, 256, 0, stream>>>(fc_w, (unsigned short*)fcwb, 1024 * 256 / 4);
  conv_kernel<<<2048, 256, 0, stream>>>(w_ih, (unsigned short*)wihb, 3072 * 1024 / 4);
  conv_kernel<<<2048, 256, 0, stream>>>(w_hh, (unsigned short*)whhb, 3072 * 1024 / 4);

  gemm_bias_kernel<256><<<dim3(16, 16), 256, 0, stream>>>(zb, fcwb, fc_b, xraw, 1024);
  ln_kernel<<<2048, 256, 0, stream>>>(xraw, ln_w, ln_b, h0);
  gemm_bias_kernel<1024><<<dim3(16, 48), 256, 0, stream>>>(h0, wihb, b_ih, gi, 3072);

  bf16* hp = h0;
  bf16* hq = h1;
  for (int t = 0; t < TSTEPS; ++t) {
    gru_step_kernel<<<dim3(16, 16), 256, 0, stream>>>(hp, hq, trueinp, tfmask, whhb, b_hh,
                                                      gi, out, t);
    bf16* tmp = hp; hp = hq; hq = tmp;
  }
}

// Round 4
// 750.648 us; speedup vs baseline: 1.5291x; 1.5291x over previous
//
#include <hip/hip_runtime.h>
#include <hip/hip_bf16.h>

#define TSTEPS 28

typedef __attribute__((ext_vector_type(8))) short bf16x8;
typedef __attribute__((ext_vector_type(4))) float f32x4;
typedef __attribute__((ext_vector_type(4))) unsigned short u16x4;
typedef __hip_bfloat16 bf16;

__device__ __forceinline__ unsigned short f2b(float f) {
  bf16 h = __float2bfloat16(f);
  return *reinterpret_cast<unsigned short*>(&h);
}
__device__ __forceinline__ float b2f(bf16 h) { return __bfloat162float(h); }

__device__ __forceinline__ void gload16(const void* g, void* l) {
  __builtin_amdgcn_global_load_lds(
      (const __attribute__((address_space(1))) void*)g,
      (__attribute__((address_space(3))) void*)l, 16, 0, 0);
}

__device__ __forceinline__ float sigm(float x) { return 1.f / (1.f + __expf(-x)); }
__device__ __forceinline__ float tanh_fast(float x) {
  const float e2 = __expf(2.f * x);
  return 1.f - 2.f / (e2 + 1.f);
}

// ---------------- f32 -> bf16 convert (vectorized) ----------------
__global__ void conv_kernel(const float* __restrict__ in, unsigned short* __restrict__ out, int n4) {
  int i = blockIdx.x * blockDim.x + threadIdx.x;
  const int stride = gridDim.x * blockDim.x;
  for (; i < n4; i += stride) {
    const float4 v = *(const float4*)&in[(size_t)i * 4];
    u16x4 o;
    o.x = f2b(v.x); o.y = f2b(v.y); o.z = f2b(v.z); o.w = f2b(v.w);
    *(u16x4*)&out[(size_t)i * 4] = o;
  }
}

// ---------------- fold whh over the 4x tiled K: whf[n][k] = sum_j whh[n][k+256j] ----------------
__global__ __launch_bounds__(256) void fold_kernel(const float* __restrict__ whh,
                                                   unsigned short* __restrict__ whf) {
  const int idx = blockIdx.x * 256 + threadIdx.x;  // 3072*64 threads, 4 k each
  const int n = idx >> 6, k4 = (idx & 63) << 2;
  const float* r = &whh[(size_t)n * 1024 + k4];
  const float4 a = *(const float4*)r;
  const float4 b = *(const float4*)(r + 256);
  const float4 c = *(const float4*)(r + 512);
  const float4 d = *(const float4*)(r + 768);
  u16x4 o;
  o.x = f2b(a.x + b.x + c.x + d.x);
  o.y = f2b(a.y + b.y + c.y + d.y);
  o.z = f2b(a.z + b.z + c.z + d.z);
  o.w = f2b(a.w + b.w + c.w + d.w);
  *(u16x4*)&whf[(size_t)n * 256 + k4] = o;
}

// ---------------- generic C = A*W^T + bias (f32 out), BM=128 BN=64 BK=32 ----------------
template <int K>
__global__ __launch_bounds__(256, 2) void gemm_bias_kernel(
    const bf16* __restrict__ A, const bf16* __restrict__ W,
    const float* __restrict__ bias, float* __restrict__ out, int Ntot) {
  constexpr int NT = K / 32;
  __shared__ __align__(16) bf16 lds[2][6144];
  const int tid = threadIdx.x;
  const int lane = tid & 63;
  const int l15 = lane & 15, l4 = lane >> 4;
  const int wid = tid >> 6, wm = wid >> 1, wn = wid & 1;
  const int m0 = blockIdx.x * 128, n0 = blockIdx.y * 64;
  const int ra = tid >> 2, cb = (tid & 3) * 8;

  f32x4 acc[4][2] = {};

  auto STAGE = [&](int buf, int kt) {
    const int k0 = kt * 32;
    gload16(&A[(size_t)(m0 + ra) * K + k0 + cb], &lds[buf][tid * 8]);
    gload16(&A[(size_t)(m0 + 64 + ra) * K + k0 + cb], &lds[buf][2048 + tid * 8]);
    gload16(&W[(size_t)(n0 + ra) * K + k0 + cb], &lds[buf][4096 + tid * 8]);
  };

  STAGE(0, 0);
  __syncthreads();
  for (int kt = 0; kt < NT; ++kt) {
    const int buf = kt & 1;
    if (kt + 1 < NT) STAGE(buf ^ 1, kt + 1);
    bf16x8 af[4], bfr[2];
#pragma unroll
    for (int m = 0; m < 4; ++m)
      af[m] = *(const bf16x8*)&lds[buf][(wm * 64 + m * 16 + l15) * 32 + l4 * 8];
#pragma unroll
    for (int n = 0; n < 2; ++n)
      bfr[n] = *(const bf16x8*)&lds[buf][4096 + (wn * 32 + n * 16 + l15) * 32 + l4 * 8];
#pragma unroll
    for (int m = 0; m < 4; ++m)
#pragma unroll
      for (int n = 0; n < 2; ++n)
        acc[m][n] = __builtin_amdgcn_mfma_f32_16x16x32_bf16(af[m], bfr[n], acc[m][n], 0, 0, 0);
    __syncthreads();
  }

#pragma unroll
  for (int m = 0; m < 4; ++m) {
#pragma unroll
    for (int n = 0; n < 2; ++n) {
      const int col = n0 + wn * 32 + n * 16 + l15;
      const int rowb = m0 + wm * 64 + m * 16 + l4 * 4;
      const float bv = bias[col];
#pragma unroll
      for (int r = 0; r < 4; ++r)
        out[(size_t)(rowb + r) * Ntot + col] = acc[m][n][r] + bv;
    }
  }
}

// ---------------- row LayerNorm -> h0 (bf16 for gi GEMM) + h0f (f32 for seq t=0) ----------------
__global__ __launch_bounds__(256) void ln_kernel(const float* __restrict__ x,
                                                 const float* __restrict__ w,
                                                 const float* __restrict__ b,
                                                 bf16* __restrict__ h0b,
                                                 float* __restrict__ h0f) {
  const int row = blockIdx.x, tid = threadIdx.x;
  const float4 v = *(const float4*)&x[(size_t)row * 1024 + tid * 4];
  float vv[4] = {v.x, v.y, v.z, v.w};
  float s = vv[0] + vv[1] + vv[2] + vv[3];
  float sq = vv[0] * vv[0] + vv[1] * vv[1] + vv[2] * vv[2] + vv[3] * vv[3];
#pragma unroll
  for (int off = 32; off; off >>= 1) {
    s += __shfl_down(s, off);
    sq += __shfl_down(sq, off);
  }
  __shared__ float sa[4], sb[4];
  const int lane = tid & 63, wid = tid >> 6;
  if (lane == 0) { sa[wid] = s; sb[wid] = sq; }
  __syncthreads();
  s = sa[0] + sa[1] + sa[2] + sa[3];
  sq = sb[0] + sb[1] + sb[2] + sb[3];
  const float mu = s * (1.f / 1024.f);
  const float var = sq * (1.f / 1024.f) - mu * mu;
  const float rs = rsqrtf(var + 1e-5f);
#pragma unroll
  for (int j = 0; j < 4; ++j) {
    const int c = tid * 4 + j;
    const float xv = (vv[j] - mu) * rs * w[c] + b[c];
    h0b[(size_t)row * 1024 + c] = __float2bfloat16(xv);
    h0f[(size_t)row * 1024 + c] = xv;
  }
}

// ---------------- batched masked steps: gh = true_inp @ whf^T (K=256), gates, out[t] ----------------
// grid (32 n-tiles, 16 m-tiles, 28 t); early-exit if mask[t]==0.
__global__ __launch_bounds__(256, 2) void batch_masked_kernel(
    const bf16* __restrict__ trueb,   // [2048][28][256] bf16
    const float* __restrict__ truef,  // [2048][28][256] f32
    const int* __restrict__ tfmask,
    const bf16* __restrict__ whf,     // [3072][256] bf16
    const float* __restrict__ bhh,
    const float* __restrict__ gi,     // [2048][3072] f32
    float* __restrict__ out) {
  const int t = blockIdx.z;
  if (tfmask[t] == 0) return;
  const int n0 = blockIdx.x * 32;
  const int m0 = blockIdx.y * 128;
  __shared__ __align__(16) bf16 lds[2][4096 + 3072];
  const int tid = threadIdx.x;
  const int lane = tid & 63, l15 = lane & 15, l4 = lane >> 4;
  const int wid = tid >> 6, wm = wid >> 1, wn = wid & 1;
  const int ra = tid >> 2, cb = (tid & 3) * 8;

  f32x4 acc[3][4] = {};

  auto STAGE = [&](int buf, int kt) {
    const int k0 = kt * 32;
    gload16(&trueb[((size_t)(m0 + ra) * TSTEPS + t) * 256 + k0 + cb], &lds[buf][tid * 8]);
    gload16(&trueb[((size_t)(m0 + 64 + ra) * TSTEPS + t) * 256 + k0 + cb], &lds[buf][2048 + tid * 8]);
#pragma unroll
    for (int j = 0; j < 2; ++j) {
      const int idx = tid + j * 256;
      if (idx < 384) {
        const int gr = idx >> 2, c2 = (idx & 3) * 8;
        gload16(&whf[(size_t)((gr >> 5) * 1024 + n0 + (gr & 31)) * 256 + k0 + c2],
                &lds[buf][4096 + idx * 8]);
      }
    }
  };

  STAGE(0, 0);
  __syncthreads();
  for (int kt = 0; kt < 8; ++kt) {
    const int buf = kt & 1;
    if (kt + 1 < 8) STAGE(buf ^ 1, kt + 1);
    bf16x8 af[4], bfr[3];
#pragma unroll
    for (int m = 0; m < 4; ++m)
      af[m] = *(const bf16x8*)&lds[buf][(wm * 64 + m * 16 + l15) * 32 + l4 * 8];
#pragma unroll
    for (int g = 0; g < 3; ++g)
      bfr[g] = *(const bf16x8*)&lds[buf][4096 + (g * 32 + wn * 16 + l15) * 32 + l4 * 8];
#pragma unroll
    for (int g = 0; g < 3; ++g)
#pragma unroll
      for (int m = 0; m < 4; ++m)
        acc[g][m] = __builtin_amdgcn_mfma_f32_16x16x32_bf16(af[m], bfr[g], acc[g][m], 0, 0, 0);
    __syncthreads();
  }

  float* outT = out + (size_t)t * 2048 * 1024;
  const int col = n0 + wn * 16 + l15;
  const float br = bhh[col], bz = bhh[col + 1024], bn_ = bhh[col + 2048];
#pragma unroll
  for (int m = 0; m < 4; ++m) {
    const int rowb = m0 + wm * 64 + m * 16 + l4 * 4;
#pragma unroll
    for (int r = 0; r < 4; ++r) {
      const int row = rowb + r;
      const float* girow = &gi[(size_t)row * 3072];
      const float ir = girow[col], iz = girow[col + 1024], inn = girow[col + 2048];
      const float hr = acc[0][m][r] + br;
      const float hz = acc[1][m][r] + bz;
      const float hn = acc[2][m][r] + bn_;
      const float hinv = truef[((size_t)row * TSTEPS + t) * 256 + (col & 255)];
      const float rg = sigm(ir + hr);
      const float ug = sigm(iz + hz);
      const float ng = tanh_fast(inn + rg * hn);
      outT[(size_t)row * 1024 + col] = (1.f - ug) * ng + ug * hinv;
    }
  }
}

// ---------------- sequential (unmasked) step: gh = prev @ whh^T (K=1024), gates, out[t] ----------------
// grid (32 n-tiles, 16 m-tiles); early-exit if mask[t]==1 (handled by batch kernel).
__global__ __launch_bounds__(256, 2) void seq_step_kernel(
    const float* __restrict__ prev,  // out[t-1] (f32) or h0f
    const int* __restrict__ tfmask,
    const bf16* __restrict__ whh,    // [3072][1024] bf16
    const float* __restrict__ bhh,
    const float* __restrict__ gi,
    float* __restrict__ out, int t) {
  if (tfmask[t] != 0) return;
  const int n0 = blockIdx.x * 32;
  const int m0 = blockIdx.y * 128;
  __shared__ __align__(16) bf16 lds[2][4096 + 3072];
  const int tid = threadIdx.x;
  const int lane = tid & 63, l15 = lane & 15, l4 = lane >> 4;
  const int wid = tid >> 6, wm = wid >> 1, wn = wid & 1;
  const int ra = tid >> 2, cb = (tid & 3) * 8;

  f32x4 acc[3][4] = {};

  auto STAGE = [&](int buf, int kt) {
    const int k0 = kt * 32;
    // A: reg-stage f32 prev -> bf16 LDS
#pragma unroll
    for (int i = 0; i < 2; ++i) {
      const float* src = &prev[(size_t)(m0 + i * 64 + ra) * 1024 + k0 + cb];
      const float4 v0 = *(const float4*)src;
      const float4 v1 = *(const float4*)(src + 4);
      bf16x8 sv;
      sv[0] = (short)f2b(v0.x); sv[1] = (short)f2b(v0.y);
      sv[2] = (short)f2b(v0.z); sv[3] = (short)f2b(v0.w);
      sv[4] = (short)f2b(v1.x); sv[5] = (short)f2b(v1.y);
      sv[6] = (short)f2b(v1.z); sv[7] = (short)f2b(v1.w);
      *(bf16x8*)&lds[buf][i * 2048 + tid * 8] = sv;
    }
    // B: whh bf16 via global_load_lds
#pragma unroll
    for (int j = 0; j < 2; ++j) {
      const int idx = tid + j * 256;
      if (idx < 384) {
        const int gr = idx >> 2, c2 = (idx & 3) * 8;
        gload16(&whh[(size_t)((gr >> 5) * 1024 + n0 + (gr & 31)) * 1024 + k0 + c2],
                &lds[buf][4096 + idx * 8]);
      }
    }
  };

  STAGE(0, 0);
  __syncthreads();
  for (int kt = 0; kt < 32; ++kt) {
    const int buf = kt & 1;
    if (kt + 1 < 32) STAGE(buf ^ 1, kt + 1);
    bf16x8 af[4], bfr[3];
#pragma unroll
    for (int m = 0; m < 4; ++m)
      af[m] = *(const bf16x8*)&lds[buf][(wm * 64 + m * 16 + l15) * 32 + l4 * 8];
#pragma unroll
    for (int g = 0; g < 3; ++g)
      bfr[g] = *(const bf16x8*)&lds[buf][4096 + (g * 32 + wn * 16 + l15) * 32 + l4 * 8];
#pragma unroll
    for (int g = 0; g < 3; ++g)
#pragma unroll
      for (int m = 0; m < 4; ++m)
        acc[g][m] = __builtin_amdgcn_mfma_f32_16x16x32_bf16(af[m], bfr[g], acc[g][m], 0, 0, 0);
    __syncthreads();
  }

  float* outT = out + (size_t)t * 2048 * 1024;
  const int col = n0 + wn * 16 + l15;
  const float br = bhh[col], bz = bhh[col + 1024], bn_ = bhh[col + 2048];
#pragma unroll
  for (int m = 0; m < 4; ++m) {
    const int rowb = m0 + wm * 64 + m * 16 + l4 * 4;
#pragma unroll
    for (int r = 0; r < 4; ++r) {
      const int row = rowb + r;
      const float* girow = &gi[(size_t)row * 3072];
      const float ir = girow[col], iz = girow[col + 1024], inn = girow[col + 2048];
      const float hr = acc[0][m][r] + br;
      const float hz = acc[1][m][r] + bz;
      const float hn = acc[2][m][r] + bn_;
      const float hinv = prev[(size_t)row * 1024 + col];
      const float rg = sigm(ir + hr);
      const float ug = sigm(iz + hz);
      const float ng = tanh_fast(inn + rg * hn);
      outT[(size_t)row * 1024 + col] = (1.f - ug) * ng + ug * hinv;
    }
  }
}

extern "C" void kernel_launch(void* const* d_in, const int* in_sizes, int n_in,
                              void* d_out, int out_size, void* d_ws, size_t ws_size,
                              hipStream_t stream) {
  (void)in_sizes; (void)n_in; (void)out_size; (void)ws_size;
  const float* z = (const float*)d_in[0];
  const float* trueinp = (const float*)d_in[1];
  const int* tfmask = (const int*)d_in[2];
  const float* fc_w = (const float*)d_in[3];
  const float* fc_b = (const float*)d_in[4];
  const float* ln_w = (const float*)d_in[5];
  const float* ln_b = (const float*)d_in[6];
  const float* w_ih = (const float*)d_in[7];
  const float* b_ih = (const float*)d_in[8];
  const float* w_hh = (const float*)d_in[9];
  const float* b_hh = (const float*)d_in[10];
  float* out = (float*)d_out;

  char* ws = (char*)d_ws;
  size_t o = 0;
  float* xraw = (float*)(ws + o); o += (size_t)2048 * 1024 * 4;
  float* h0f  = (float*)(ws + o); o += (size_t)2048 * 1024 * 4;
  float* gi   = (float*)(ws + o); o += (size_t)2048 * 3072 * 4;
  bf16* h0b   = (bf16*)(ws + o);  o += (size_t)2048 * 1024 * 2;
  bf16* zb    = (bf16*)(ws + o);  o += (size_t)2048 * 256 * 2;
  bf16* fcwb  = (bf16*)(ws + o);  o += (size_t)1024 * 256 * 2;
  bf16* wihb  = (bf16*)(ws + o);  o += (size_t)3072 * 1024 * 2;
  bf16* whhb  = (bf16*)(ws + o);  o += (size_t)3072 * 1024 * 2;
  bf16* whf   = (bf16*)(ws + o);  o += (size_t)3072 * 256 * 2;
  bf16* trueb = (bf16*)(ws + o);  o += (size_t)2048 * TSTEPS * 256 * 2;

  conv_kernel<<<1024, 256, 0, stream>>>(z, (unsigned short*)zb, 2048 * 256 / 4);
  conv_kernel<<<512, 256, 0, stream>>>(fc_w, (unsigned short*)fcwb, 1024 * 256 / 4);
  conv_kernel<<<2048, 256, 0, stream>>>(w_ih, (unsigned short*)wihb, 3072 * 1024 / 4);
  conv_kernel<<<2048, 256, 0, stream>>>(w_hh, (unsigned short*)whhb, 3072 * 1024 / 4);
  conv_kernel<<<2048, 256, 0, stream>>>(trueinp, (unsigned short*)trueb, 2048 * TSTEPS * 256 / 4);
  fold_kernel<<<768, 256, 0, stream>>>(w_hh, (unsigned short*)whf);

  gemm_bias_kernel<256><<<dim3(16, 16), 256, 0, stream>>>(zb, fcwb, fc_b, xraw, 1024);
  ln_kernel<<<2048, 256, 0, stream>>>(xraw, ln_w, ln_b, h0b, h0f);
  gemm_bias_kernel<1024><<<dim3(16, 48), 256, 0, stream>>>(h0b, wihb, b_ih, gi, 3072);

  batch_masked_kernel<<<dim3(32, 16, TSTEPS), 256, 0, stream>>>(trueb, trueinp, tfmask, whf,
                                                                b_hh, gi, out);

  const float* prev = h0f;
  for (int t = 0; t < TSTEPS; ++t) {
    seq_step_kernel<<<dim3(32, 16), 256, 0, stream>>>(prev, tfmask, whhb, b_hh, gi, out, t);
    prev = out + (size_t)t * 2048 * 1024;
  }
}

// Round 5
// 735.060 us; speedup vs baseline: 1.5616x; 1.0212x over previous
//
#include <hip/hip_runtime.h>
#include <hip/hip_bf16.h>

#define TSTEPS 28

typedef __attribute__((ext_vector_type(8))) short bf16x8;
typedef __attribute__((ext_vector_type(4))) float f32x4;
typedef __attribute__((ext_vector_type(4))) unsigned short u16x4;
typedef __hip_bfloat16 bf16;

__device__ __forceinline__ unsigned short f2b(float f) {
  bf16 h = __float2bfloat16(f);
  return *reinterpret_cast<unsigned short*>(&h);
}

__device__ __forceinline__ void gload16(const void* g, void* l) {
  __builtin_amdgcn_global_load_lds(
      (const __attribute__((address_space(1))) void*)g,
      (__attribute__((address_space(3))) void*)l, 16, 0, 0);
}

__device__ __forceinline__ float sigm(float x) { return 1.f / (1.f + __expf(-x)); }
__device__ __forceinline__ float tanh_fast(float x) {
  const float e2 = __expf(2.f * x);
  return 1.f - 2.f / (e2 + 1.f);
}

// ---------------- f32 -> bf16 convert (vectorized) ----------------
__global__ void conv_kernel(const float* __restrict__ in, unsigned short* __restrict__ out, int n4) {
  int i = blockIdx.x * blockDim.x + threadIdx.x;
  const int stride = gridDim.x * blockDim.x;
  for (; i < n4; i += stride) {
    const float4 v = *(const float4*)&in[(size_t)i * 4];
    u16x4 o;
    o.x = f2b(v.x); o.y = f2b(v.y); o.z = f2b(v.z); o.w = f2b(v.w);
    *(u16x4*)&out[(size_t)i * 4] = o;
  }
}

// ---------------- fold whh over the 4x tiled K: whf[n][k] = sum_j whh[n][k+256j] ----------------
__global__ __launch_bounds__(256) void fold_kernel(const float* __restrict__ whh,
                                                   unsigned short* __restrict__ whf) {
  const int idx = blockIdx.x * 256 + threadIdx.x;
  const int n = idx >> 6, k4 = (idx & 63) << 2;
  const float* r = &whh[(size_t)n * 1024 + k4];
  const float4 a = *(const float4*)r;
  const float4 b = *(const float4*)(r + 256);
  const float4 c = *(const float4*)(r + 512);
  const float4 d = *(const float4*)(r + 768);
  u16x4 o;
  o.x = f2b(a.x + b.x + c.x + d.x);
  o.y = f2b(a.y + b.y + c.y + d.y);
  o.z = f2b(a.z + b.z + c.z + d.z);
  o.w = f2b(a.w + b.w + c.w + d.w);
  *(u16x4*)&whf[(size_t)n * 256 + k4] = o;
}

// ---------------- generic C = A*W^T + bias (f32 out), BM=128 BN=64 BK=32 ----------------
template <int K>
__global__ __launch_bounds__(256, 2) void gemm_bias_kernel(
    const bf16* __restrict__ A, const bf16* __restrict__ W,
    const float* __restrict__ bias, float* __restrict__ out, int Ntot) {
  constexpr int NT = K / 32;
  __shared__ __align__(16) bf16 lds[2][6144];
  const int tid = threadIdx.x;
  const int lane = tid & 63;
  const int l15 = lane & 15, l4 = lane >> 4;
  const int wid = tid >> 6, wm = wid >> 1, wn = wid & 1;
  const int m0 = blockIdx.x * 128, n0 = blockIdx.y * 64;
  const int ra = tid >> 2, cb = (tid & 3) * 8;

  f32x4 acc[4][2] = {};

  auto STAGE = [&](int buf, int kt) {
    const int k0 = kt * 32;
    gload16(&A[(size_t)(m0 + ra) * K + k0 + cb], &lds[buf][tid * 8]);
    gload16(&A[(size_t)(m0 + 64 + ra) * K + k0 + cb], &lds[buf][2048 + tid * 8]);
    gload16(&W[(size_t)(n0 + ra) * K + k0 + cb], &lds[buf][4096 + tid * 8]);
  };

  STAGE(0, 0);
  __syncthreads();
  for (int kt = 0; kt < NT; ++kt) {
    const int buf = kt & 1;
    if (kt + 1 < NT) STAGE(buf ^ 1, kt + 1);
    bf16x8 af[4], bfr[2];
#pragma unroll
    for (int m = 0; m < 4; ++m)
      af[m] = *(const bf16x8*)&lds[buf][(wm * 64 + m * 16 + l15) * 32 + l4 * 8];
#pragma unroll
    for (int n = 0; n < 2; ++n)
      bfr[n] = *(const bf16x8*)&lds[buf][4096 + (wn * 32 + n * 16 + l15) * 32 + l4 * 8];
#pragma unroll
    for (int m = 0; m < 4; ++m)
#pragma unroll
      for (int n = 0; n < 2; ++n)
        acc[m][n] = __builtin_amdgcn_mfma_f32_16x16x32_bf16(af[m], bfr[n], acc[m][n], 0, 0, 0);
    __syncthreads();
  }

#pragma unroll
  for (int m = 0; m < 4; ++m) {
#pragma unroll
    for (int n = 0; n < 2; ++n) {
      const int col = n0 + wn * 32 + n * 16 + l15;
      const int rowb = m0 + wm * 64 + m * 16 + l4 * 4;
      const float bv = bias[col];
#pragma unroll
      for (int r = 0; r < 4; ++r)
        out[(size_t)(rowb + r) * Ntot + col] = acc[m][n][r] + bv;
    }
  }
}

// ---------------- row LayerNorm -> h0b (bf16) + h0f (f32) ----------------
__global__ __launch_bounds__(256) void ln_kernel(const float* __restrict__ x,
                                                 const float* __restrict__ w,
                                                 const float* __restrict__ b,
                                                 bf16* __restrict__ h0b,
                                                 float* __restrict__ h0f) {
  const int row = blockIdx.x, tid = threadIdx.x;
  const float4 v = *(const float4*)&x[(size_t)row * 1024 + tid * 4];
  float vv[4] = {v.x, v.y, v.z, v.w};
  float s = vv[0] + vv[1] + vv[2] + vv[3];
  float sq = vv[0] * vv[0] + vv[1] * vv[1] + vv[2] * vv[2] + vv[3] * vv[3];
#pragma unroll
  for (int off = 32; off; off >>= 1) {
    s += __shfl_down(s, off);
    sq += __shfl_down(sq, off);
  }
  __shared__ float sa[4], sb[4];
  const int lane = tid & 63, wid = tid >> 6;
  if (lane == 0) { sa[wid] = s; sb[wid] = sq; }
  __syncthreads();
  s = sa[0] + sa[1] + sa[2] + sa[3];
  sq = sb[0] + sb[1] + sb[2] + sb[3];
  const float mu = s * (1.f / 1024.f);
  const float var = sq * (1.f / 1024.f) - mu * mu;
  const float rs = rsqrtf(var + 1e-5f);
#pragma unroll
  for (int j = 0; j < 4; ++j) {
    const int c = tid * 4 + j;
    const float xv = (vv[j] - mu) * rs * w[c] + b[c];
    h0b[(size_t)row * 1024 + c] = __float2bfloat16(xv);
    h0f[(size_t)row * 1024 + c] = xv;
  }
}

// ---------------- unified GRU step (masked: K=256 folded; unmasked: K=1024) ----------------
// grid (16,16) x 512 threads: BM=128, BN=64 (x3 gates), 8 waves (2m x 4n).
// XCD swizzle: each XCD owns 2 n-tiles x all 16 m-tiles -> its whh slice (768KB) L2-resident.
__global__ __launch_bounds__(512, 2) void step_kernel(
    const bf16* __restrict__ prevb,   // bf16 h[t-1] (hbf ping-pong or h0b)
    const float* __restrict__ prevf,  // f32 h[t-1] (out[t-1] or h0f) for the u*h term
    const bf16* __restrict__ trueb,   // [2048][28][256] bf16
    const float* __restrict__ truef,  // [2048][28][256] f32
    const int* __restrict__ tfmask,
    const bf16* __restrict__ whh,     // [3072][1024] bf16
    const bf16* __restrict__ whf,     // [3072][256] bf16 (K-folded)
    const float* __restrict__ bhh,
    const float* __restrict__ gi,     // [2048][3072] f32
    float* __restrict__ out,          // full output base
    bf16* __restrict__ hbf,           // bf16 h[t] destination
    int t) {
  const bool masked = tfmask[t] != 0;
  const int bid = blockIdx.x + blockIdx.y * 16;
  const int sw = (bid & 7) * 32 + (bid >> 3);
  const int n0 = (sw >> 4) * 64;   // n-chunked per XCD
  const int m0 = (sw & 15) * 128;

  __shared__ __align__(16) bf16 lds[2][10240];  // A 128x32 (4096) + B 192x32 (6144)
  const int tid = threadIdx.x;
  const int lane = tid & 63, l15 = lane & 15, l4 = lane >> 4;
  const int wid = tid >> 6, wm = wid >> 2, wn = wid & 3;

  f32x4 acc[3][4] = {};

  const bf16* Asrc;
  size_t astride;
  const bf16* Bsrc;
  int kdim, NT;
  if (masked) {
    Asrc = trueb + (size_t)t * 256; astride = (size_t)TSTEPS * 256;
    Bsrc = whf; kdim = 256; NT = 8;
  } else {
    Asrc = prevb; astride = 1024;
    Bsrc = whh; kdim = 1024; NT = 32;
  }

  auto STAGE = [&](int buf, int kt) {
    const int k0 = kt * 32;
    // A: 128 rows x 32 cols, one 16B chunk per thread
    gload16(&Asrc[(size_t)(m0 + (tid >> 2)) * astride + k0 + (tid & 3) * 8],
            &lds[buf][tid * 8]);
    // B: 192 rows (3 gates x 64) x 32 cols = 768 chunks
    {
      const int r = tid >> 2, c8 = (tid & 3) * 8;
      gload16(&Bsrc[(size_t)((r >> 6) * 1024 + n0 + (r & 63)) * kdim + k0 + c8],
              &lds[buf][4096 + tid * 8]);
    }
    if (tid < 256) {
      const int idx = 512 + tid;
      const int r = idx >> 2, c8 = (idx & 3) * 8;
      gload16(&Bsrc[(size_t)((r >> 6) * 1024 + n0 + (r & 63)) * kdim + k0 + c8],
              &lds[buf][4096 + idx * 8]);
    }
  };

  STAGE(0, 0);
  __syncthreads();
  for (int kt = 0; kt < NT; ++kt) {
    const int buf = kt & 1;
    if (kt + 1 < NT) STAGE(buf ^ 1, kt + 1);
    bf16x8 af[4], bfr[3];
#pragma unroll
    for (int m = 0; m < 4; ++m)
      af[m] = *(const bf16x8*)&lds[buf][(wm * 64 + m * 16 + l15) * 32 + l4 * 8];
#pragma unroll
    for (int g = 0; g < 3; ++g)
      bfr[g] = *(const bf16x8*)&lds[buf][4096 + (g * 64 + wn * 16 + l15) * 32 + l4 * 8];
#pragma unroll
    for (int g = 0; g < 3; ++g)
#pragma unroll
      for (int m = 0; m < 4; ++m)
        acc[g][m] = __builtin_amdgcn_mfma_f32_16x16x32_bf16(af[m], bfr[g], acc[g][m], 0, 0, 0);
    __syncthreads();
  }

  float* outT = out + (size_t)t * 2048 * 1024;
  const int col = n0 + wn * 16 + l15;
  const float br = bhh[col], bz = bhh[col + 1024], bn_ = bhh[col + 2048];
#pragma unroll
  for (int m = 0; m < 4; ++m) {
    const int rowb = m0 + wm * 64 + m * 16 + l4 * 4;
#pragma unroll
    for (int r = 0; r < 4; ++r) {
      const int row = rowb + r;
      const float* girow = &gi[(size_t)row * 3072];
      const float ir = girow[col], iz = girow[col + 1024], inn = girow[col + 2048];
      const float hr = acc[0][m][r] + br;
      const float hz = acc[1][m][r] + bz;
      const float hn = acc[2][m][r] + bn_;
      const float hinv = masked ? truef[((size_t)row * TSTEPS + t) * 256 + (col & 255)]
                                : prevf[(size_t)row * 1024 + col];
      const float rg = sigm(ir + hr);
      const float ug = sigm(iz + hz);
      const float ng = tanh_fast(inn + rg * hn);
      const float hnew = (1.f - ug) * ng + ug * hinv;
      outT[(size_t)row * 1024 + col] = hnew;
      hbf[(size_t)row * 1024 + col] = __float2bfloat16(hnew);
    }
  }
}

extern "C" void kernel_launch(void* const* d_in, const int* in_sizes, int n_in,
                              void* d_out, int out_size, void* d_ws, size_t ws_size,
                              hipStream_t stream) {
  (void)in_sizes; (void)n_in; (void)out_size; (void)ws_size;
  const float* z = (const float*)d_in[0];
  const float* trueinp = (const float*)d_in[1];
  const int* tfmask = (const int*)d_in[2];
  const float* fc_w = (const float*)d_in[3];
  const float* fc_b = (const float*)d_in[4];
  const float* ln_w = (const float*)d_in[5];
  const float* ln_b = (const float*)d_in[6];
  const float* w_ih = (const float*)d_in[7];
  const float* b_ih = (const float*)d_in[8];
  const float* w_hh = (const float*)d_in[9];
  const float* b_hh = (const float*)d_in[10];
  float* out = (float*)d_out;

  char* ws = (char*)d_ws;
  size_t o = 0;
  float* xraw = (float*)(ws + o); o += (size_t)2048 * 1024 * 4;
  float* h0f  = (float*)(ws + o); o += (size_t)2048 * 1024 * 4;
  float* gi   = (float*)(ws + o); o += (size_t)2048 * 3072 * 4;
  bf16* h0b   = (bf16*)(ws + o);  o += (size_t)2048 * 1024 * 2;
  bf16* hbf0  = (bf16*)(ws + o);  o += (size_t)2048 * 1024 * 2;
  bf16* hbf1  = (bf16*)(ws + o);  o += (size_t)2048 * 1024 * 2;
  bf16* zb    = (bf16*)(ws + o);  o += (size_t)2048 * 256 * 2;
  bf16* fcwb  = (bf16*)(ws + o);  o += (size_t)1024 * 256 * 2;
  bf16* wihb  = (bf16*)(ws + o);  o += (size_t)3072 * 1024 * 2;
  bf16* whhb  = (bf16*)(ws + o);  o += (size_t)3072 * 1024 * 2;
  bf16* whf   = (bf16*)(ws + o);  o += (size_t)3072 * 256 * 2;
  bf16* trueb = (bf16*)(ws + o);  o += (size_t)2048 * TSTEPS * 256 * 2;

  conv_kernel<<<1024, 256, 0, stream>>>(z, (unsigned short*)zb, 2048 * 256 / 4);
  conv_kernel<<<512, 256, 0, stream>>>(fc_w, (unsigned short*)fcwb, 1024 * 256 / 4);
  conv_kernel<<<2048, 256, 0, stream>>>(w_ih, (unsigned short*)wihb, 3072 * 1024 / 4);
  conv_kernel<<<2048, 256, 0, stream>>>(w_hh, (unsigned short*)whhb, 3072 * 1024 / 4);
  conv_kernel<<<2048, 256, 0, stream>>>(trueinp, (unsigned short*)trueb, 2048 * TSTEPS * 256 / 4);
  fold_kernel<<<768, 256, 0, stream>>>(w_hh, (unsigned short*)whf);

  gemm_bias_kernel<256><<<dim3(16, 16), 256, 0, stream>>>(zb, fcwb, fc_b, xraw, 1024);
  ln_kernel<<<2048, 256, 0, stream>>>(xraw, ln_w, ln_b, h0b, h0f);
  gemm_bias_kernel<1024><<<dim3(16, 48), 256, 0, stream>>>(h0b, wihb, b_ih, gi, 3072);

  const bf16* prevb = h0b;
  const float* prevf = h0f;
  bf16* hcur = hbf0;
  for (int t = 0; t < TSTEPS; ++t) {
    step_kernel<<<dim3(16, 16), 512, 0, stream>>>(prevb, prevf, trueb, trueinp, tfmask,
                                                  whhb, whf, b_hh, gi, out, hcur, t);
    prevb = hcur;
    prevf = out + (size_t)t * 2048 * 1024;
    hcur = (hcur == hbf0) ? hbf1 : hbf0;
  }
}

// Round 8
// 711.273 us; speedup vs baseline: 1.6138x; 1.0334x over previous
//
#include <hip/hip_runtime.h>
#include <hip/hip_bf16.h>

#define TSTEPS 28

typedef __attribute__((ext_vector_type(8))) short bf16x8;
typedef __attribute__((ext_vector_type(4))) float f32x4;
typedef __attribute__((ext_vector_type(4))) unsigned short u16x4;
typedef __hip_bfloat16 bf16;

__device__ __forceinline__ unsigned short f2b(float f) {
  bf16 h = __float2bfloat16(f);
  return *reinterpret_cast<unsigned short*>(&h);
}

__device__ __forceinline__ void gload16(const void* g, void* l) {
  __builtin_amdgcn_global_load_lds(
      (const __attribute__((address_space(1))) void*)g,
      (__attribute__((address_space(3))) void*)l, 16, 0, 0);
}

__device__ __forceinline__ float sigm(float x) { return 1.f / (1.f + __expf(-x)); }
__device__ __forceinline__ float tanh_fast(float x) {
  const float e2 = __expf(2.f * x);
  return 1.f - 2.f / (e2 + 1.f);
}

// ---------------- f32 -> bf16 convert (vectorized) ----------------
__global__ void conv_kernel(const float* __restrict__ in, unsigned short* __restrict__ out, int n4) {
  int i = blockIdx.x * blockDim.x + threadIdx.x;
  const int stride = gridDim.x * blockDim.x;
  for (; i < n4; i += stride) {
    const float4 v = *(const float4*)&in[(size_t)i * 4];
    u16x4 o;
    o.x = f2b(v.x); o.y = f2b(v.y); o.z = f2b(v.z); o.w = f2b(v.w);
    *(u16x4*)&out[(size_t)i * 4] = o;
  }
}

// ---------------- fold whh over the 4x tiled K: whf[n][k] = sum_j whh[n][k+256j] ----------------
__global__ __launch_bounds__(256) void fold_kernel(const float* __restrict__ whh,
                                                   unsigned short* __restrict__ whf) {
  const int idx = blockIdx.x * 256 + threadIdx.x;
  const int n = idx >> 6, k4 = (idx & 63) << 2;
  const float* r = &whh[(size_t)n * 1024 + k4];
  const float4 a = *(const float4*)r;
  const float4 b = *(const float4*)(r + 256);
  const float4 c = *(const float4*)(r + 512);
  const float4 d = *(const float4*)(r + 768);
  u16x4 o;
  o.x = f2b(a.x + b.x + c.x + d.x);
  o.y = f2b(a.y + b.y + c.y + d.y);
  o.z = f2b(a.z + b.z + c.z + d.z);
  o.w = f2b(a.w + b.w + c.w + d.w);
  *(u16x4*)&whf[(size_t)n * 256 + k4] = o;
}

// ---------------- fc GEMM: C = A*W^T + bias (f32 out), BM=128 BN=64 BK=32, K=256 ----------------
__global__ __launch_bounds__(256, 2) void gemm_fc_kernel(
    const bf16* __restrict__ A, const bf16* __restrict__ W,
    const float* __restrict__ bias, float* __restrict__ out) {
  constexpr int K = 256, NT = K / 32;
  __shared__ __align__(16) bf16 lds[2][6144];
  const int tid = threadIdx.x;
  const int lane = tid & 63;
  const int l15 = lane & 15, l4 = lane >> 4;
  const int wid = tid >> 6, wm = wid >> 1, wn = wid & 1;
  const int m0 = blockIdx.x * 128, n0 = blockIdx.y * 64;
  const int ra = tid >> 2, cb = (tid & 3) * 8;

  f32x4 acc[4][2] = {};

  auto STAGE = [&](int buf, int kt) {
    const int k0 = kt * 32;
    gload16(&A[(size_t)(m0 + ra) * K + k0 + cb], &lds[buf][tid * 8]);
    gload16(&A[(size_t)(m0 + 64 + ra) * K + k0 + cb], &lds[buf][2048 + tid * 8]);
    gload16(&W[(size_t)(n0 + ra) * K + k0 + cb], &lds[buf][4096 + tid * 8]);
  };

  STAGE(0, 0);
  __syncthreads();
  for (int kt = 0; kt < NT; ++kt) {
    const int buf = kt & 1;
    if (kt + 1 < NT) STAGE(buf ^ 1, kt + 1);
    bf16x8 af[4], bfr[2];
#pragma unroll
    for (int m = 0; m < 4; ++m)
      af[m] = *(const bf16x8*)&lds[buf][(wm * 64 + m * 16 + l15) * 32 + l4 * 8];
#pragma unroll
    for (int n = 0; n < 2; ++n)
      bfr[n] = *(const bf16x8*)&lds[buf][4096 + (wn * 32 + n * 16 + l15) * 32 + l4 * 8];
#pragma unroll
    for (int m = 0; m < 4; ++m)
#pragma unroll
      for (int n = 0; n < 2; ++n)
        acc[m][n] = __builtin_amdgcn_mfma_f32_16x16x32_bf16(af[m], bfr[n], acc[m][n], 0, 0, 0);
    __syncthreads();
  }

#pragma unroll
  for (int m = 0; m < 4; ++m) {
#pragma unroll
    for (int n = 0; n < 2; ++n) {
      const int col = n0 + wn * 32 + n * 16 + l15;
      const int rowb = m0 + wm * 64 + m * 16 + l4 * 4;
      const float bv = bias[col];
#pragma unroll
      for (int r = 0; r < 4; ++r)
        out[(size_t)(rowb + r) * 1024 + col] = acc[m][n][r] + bv;
    }
  }
}

// ---------------- row LayerNorm -> h0b (bf16) + h0f (f32) ----------------
__global__ __launch_bounds__(256) void ln_kernel(const float* __restrict__ x,
                                                 const float* __restrict__ w,
                                                 const float* __restrict__ b,
                                                 bf16* __restrict__ h0b,
                                                 float* __restrict__ h0f) {
  const int row = blockIdx.x, tid = threadIdx.x;
  const float4 v = *(const float4*)&x[(size_t)row * 1024 + tid * 4];
  float vv[4] = {v.x, v.y, v.z, v.w};
  float s = vv[0] + vv[1] + vv[2] + vv[3];
  float sq = vv[0] * vv[0] + vv[1] * vv[1] + vv[2] * vv[2] + vv[3] * vv[3];
#pragma unroll
  for (int off = 32; off; off >>= 1) {
    s += __shfl_down(s, off);
    sq += __shfl_down(sq, off);
  }
  __shared__ float sa[4], sb[4];
  const int lane = tid & 63, wid = tid >> 6;
  if (lane == 0) { sa[wid] = s; sb[wid] = sq; }
  __syncthreads();
  s = sa[0] + sa[1] + sa[2] + sa[3];
  sq = sb[0] + sb[1] + sb[2] + sb[3];
  const float mu = s * (1.f / 1024.f);
  const float var = sq * (1.f / 1024.f) - mu * mu;
  const float rs = rsqrtf(var + 1e-5f);
#pragma unroll
  for (int j = 0; j < 4; ++j) {
    const int c = tid * 4 + j;
    const float xv = (vv[j] - mu) * rs * w[c] + b[c];
    h0b[(size_t)row * 1024 + c] = __float2bfloat16(xv);
    h0f[(size_t)row * 1024 + c] = xv;
  }
}

// ---------------- gi GEMM: gi = h0b @ w_ih^T + b_ih. BM=64, 192 B-rows (3 gates), K=1024 ----------------
// grid (16,32) = 512 blocks (2/CU), 256 threads.
__global__ __launch_bounds__(256, 2) void gemm_gi_kernel(
    const bf16* __restrict__ A,      // [2048][1024] bf16
    const bf16* __restrict__ W,      // [3072][1024] bf16
    const float* __restrict__ bias,  // [3072]
    float* __restrict__ out) {       // [2048][3072]
  __shared__ __align__(16) bf16 lds[2][8192];  // A 64x32 (2048) + B 192x32 (6144)
  const int tid = threadIdx.x;
  const int lane = tid & 63, l15 = lane & 15, l4 = lane >> 4;
  const int wid = tid >> 6;
  const int n0 = blockIdx.x * 64, m0 = blockIdx.y * 64;

  f32x4 acc[3][4] = {};

  auto STAGE = [&](int buf, int kt) {
    const int k0 = kt * 32;
    gload16(&A[(size_t)(m0 + (tid >> 2)) * 1024 + k0 + (tid & 3) * 8], &lds[buf][tid * 8]);
#pragma unroll
    for (int j = 0; j < 3; ++j) {
      const int c = tid + j * 256;
      const int r = c >> 2, c8 = (c & 3) * 8;
      gload16(&W[(size_t)((r >> 6) * 1024 + n0 + (r & 63)) * 1024 + k0 + c8],
              &lds[buf][2048 + c * 8]);
    }
  };

  STAGE(0, 0);
  __syncthreads();
  for (int kt = 0; kt < 32; ++kt) {
    const int buf = kt & 1;
    if (kt + 1 < 32) STAGE(buf ^ 1, kt + 1);
    bf16x8 af[4], bfr[3];
#pragma unroll
    for (int m = 0; m < 4; ++m)
      af[m] = *(const bf16x8*)&lds[buf][(m * 16 + l15) * 32 + l4 * 8];
#pragma unroll
    for (int g = 0; g < 3; ++g)
      bfr[g] = *(const bf16x8*)&lds[buf][2048 + (g * 64 + wid * 16 + l15) * 32 + l4 * 8];
#pragma unroll
    for (int g = 0; g < 3; ++g)
#pragma unroll
      for (int m = 0; m < 4; ++m)
        acc[g][m] = __builtin_amdgcn_mfma_f32_16x16x32_bf16(af[m], bfr[g], acc[g][m], 0, 0, 0);
    __syncthreads();
  }

  const int col = n0 + wid * 16 + l15;
#pragma unroll
  for (int g = 0; g < 3; ++g) {
    const float bv = bias[g * 1024 + col];
#pragma unroll
    for (int m = 0; m < 4; ++m) {
      const int rowb = m0 + m * 16 + l4 * 4;
#pragma unroll
      for (int r = 0; r < 4; ++r)
        out[(size_t)(rowb + r) * 3072 + g * 1024 + col] = acc[g][m][r] + bv;
    }
  }
}

// ---------------- batched masked steps: K=256 folded whf. grid (16,32,28), early-exit ----------------
__global__ __launch_bounds__(256, 2) void batch_masked_kernel(
    const bf16* __restrict__ trueb,   // [2048][28][256] bf16
    const float* __restrict__ truef,  // [2048][28][256] f32
    const int* __restrict__ tfmask,
    const bf16* __restrict__ whf,     // [3072][256] bf16
    const float* __restrict__ bhh,
    const float* __restrict__ gi,     // [2048][3072]
    float* __restrict__ out) {
  const int t = blockIdx.z;
  if (tfmask[t] == 0) return;
  __shared__ __align__(16) bf16 lds[2][8192];
  const int tid = threadIdx.x;
  const int lane = tid & 63, l15 = lane & 15, l4 = lane >> 4;
  const int wid = tid >> 6;
  const int n0 = blockIdx.x * 64, m0 = blockIdx.y * 64;

  f32x4 acc[3][4] = {};

  auto STAGE = [&](int buf, int kt) {
    const int k0 = kt * 32;
    gload16(&trueb[((size_t)(m0 + (tid >> 2)) * TSTEPS + t) * 256 + k0 + (tid & 3) * 8],
            &lds[buf][tid * 8]);
#pragma unroll
    for (int j = 0; j < 3; ++j) {
      const int c = tid + j * 256;
      const int r = c >> 2, c8 = (c & 3) * 8;
      gload16(&whf[(size_t)((r >> 6) * 1024 + n0 + (r & 63)) * 256 + k0 + c8],
              &lds[buf][2048 + c * 8]);
    }
  };

  STAGE(0, 0);
  __syncthreads();
  for (int kt = 0; kt < 8; ++kt) {
    const int buf = kt & 1;
    if (kt + 1 < 8) STAGE(buf ^ 1, kt + 1);
    bf16x8 af[4], bfr[3];
#pragma unroll
    for (int m = 0; m < 4; ++m)
      af[m] = *(const bf16x8*)&lds[buf][(m * 16 + l15) * 32 + l4 * 8];
#pragma unroll
    for (int g = 0; g < 3; ++g)
      bfr[g] = *(const bf16x8*)&lds[buf][2048 + (g * 64 + wid * 16 + l15) * 32 + l4 * 8];
#pragma unroll
    for (int g = 0; g < 3; ++g)
#pragma unroll
      for (int m = 0; m < 4; ++m)
        acc[g][m] = __builtin_amdgcn_mfma_f32_16x16x32_bf16(af[m], bfr[g], acc[g][m], 0, 0, 0);
    __syncthreads();
  }

  float* outT = out + (size_t)t * 2048 * 1024;
  const int col = n0 + wid * 16 + l15;
  const float br = bhh[col], bz = bhh[col + 1024], bn_ = bhh[col + 2048];
#pragma unroll
  for (int m = 0; m < 4; ++m) {
    const int rowb = m0 + m * 16 + l4 * 4;
#pragma unroll
    for (int r = 0; r < 4; ++r) {
      const int row = rowb + r;
      const float* girow = &gi[(size_t)row * 3072];
      const float ir = girow[col], iz = girow[col + 1024], inn = girow[col + 2048];
      const float hr = acc[0][m][r] + br;
      const float hz = acc[1][m][r] + bz;
      const float hn = acc[2][m][r] + bn_;
      const float hinv = truef[((size_t)row * TSTEPS + t) * 256 + (col & 255)];
      const float rg = sigm(ir + hr);
      const float ug = sigm(iz + hz);
      const float ng = tanh_fast(inn + rg * hn);
      outT[(size_t)row * 1024 + col] = (1.f - ug) * ng + ug * hinv;
    }
  }
}

// ---------------- sequential unmasked step: A = out[t-1] (f32, reg-staged), K=1024 ----------------
// grid 512 linear (XCD-swizzled: XCD k owns n-tiles {2k,2k+1}), 256 threads, 2 blocks/CU.
__global__ __launch_bounds__(256, 2) void step_kernel(
    const float* __restrict__ prevf,  // out[t-1] f32 (or h0f at t=0)
    const int* __restrict__ tfmask,
    const bf16* __restrict__ whh,     // [3072][1024] bf16
    const float* __restrict__ bhh,
    const float* __restrict__ gi,
    float* __restrict__ out, int t) {
  if (tfmask[t] != 0) return;
  const int lid = blockIdx.x;
  const int xcd = lid & 7, rest = lid >> 3;
  const int m0 = (rest & 31) * 64;
  const int n0 = ((xcd << 1) | (rest >> 5)) * 64;

  __shared__ __align__(16) bf16 lds[2][8192];  // A 64x32 + B 192x32
  const int tid = threadIdx.x;
  const int lane = tid & 63, l15 = lane & 15, l4 = lane >> 4;
  const int wid = tid >> 6;

  f32x4 acc[3][4] = {};

  auto STAGE = [&](int buf, int kt) {
    const int k0 = kt * 32;
    // A: reg-stage f32 -> bf16 (64 rows x 32 cols, 1 chunk of 8 per thread)
    {
      const float* src = &prevf[(size_t)(m0 + (tid >> 2)) * 1024 + k0 + (tid & 3) * 8];
      const float4 v0 = *(const float4*)src;
      const float4 v1 = *(const float4*)(src + 4);
      bf16x8 sv;
      sv[0] = (short)f2b(v0.x); sv[1] = (short)f2b(v0.y);
      sv[2] = (short)f2b(v0.z); sv[3] = (short)f2b(v0.w);
      sv[4] = (short)f2b(v1.x); sv[5] = (short)f2b(v1.y);
      sv[6] = (short)f2b(v1.z); sv[7] = (short)f2b(v1.w);
      *(bf16x8*)&lds[buf][tid * 8] = sv;
    }
    // B: 192 rows x 32 cols via global_load_lds, 3 chunks/thread
#pragma unroll
    for (int j = 0; j < 3; ++j) {
      const int c = tid + j * 256;
      const int r = c >> 2, c8 = (c & 3) * 8;
      gload16(&whh[(size_t)((r >> 6) * 1024 + n0 + (r & 63)) * 1024 + k0 + c8],
              &lds[buf][2048 + c * 8]);
    }
  };

  STAGE(0, 0);
  __syncthreads();
  for (int kt = 0; kt < 32; ++kt) {
    const int buf = kt & 1;
    if (kt + 1 < 32) STAGE(buf ^ 1, kt + 1);
    bf16x8 af[4], bfr[3];
#pragma unroll
    for (int m = 0; m < 4; ++m)
      af[m] = *(const bf16x8*)&lds[buf][(m * 16 + l15) * 32 + l4 * 8];
#pragma unroll
    for (int g = 0; g < 3; ++g)
      bfr[g] = *(const bf16x8*)&lds[buf][2048 + (g * 64 + wid * 16 + l15) * 32 + l4 * 8];
#pragma unroll
    for (int g = 0; g < 3; ++g)
#pragma unroll
      for (int m = 0; m < 4; ++m)
        acc[g][m] = __builtin_amdgcn_mfma_f32_16x16x32_bf16(af[m], bfr[g], acc[g][m], 0, 0, 0);
    __syncthreads();
  }

  float* outT = out + (size_t)t * 2048 * 1024;
  const int col = n0 + wid * 16 + l15;
  const float br = bhh[col], bz = bhh[col + 1024], bn_ = bhh[col + 2048];
#pragma unroll
  for (int m = 0; m < 4; ++m) {
    const int rowb = m0 + m * 16 + l4 * 4;
#pragma unroll
    for (int r = 0; r < 4; ++r) {
      const int row = rowb + r;
      const float* girow = &gi[(size_t)row * 3072];
      const float ir = girow[col], iz = girow[col + 1024], inn = girow[col + 2048];
      const float hr = acc[0][m][r] + br;
      const float hz = acc[1][m][r] + bz;
      const float hn = acc[2][m][r] + bn_;
      const float hinv = prevf[(size_t)row * 1024 + col];
      const float rg = sigm(ir + hr);
      const float ug = sigm(iz + hz);
      const float ng = tanh_fast(inn + rg * hn);
      outT[(size_t)row * 1024 + col] = (1.f - ug) * ng + ug * hinv;
    }
  }
}

extern "C" void kernel_launch(void* const* d_in, const int* in_sizes, int n_in,
                              void* d_out, int out_size, void* d_ws, size_t ws_size,
                              hipStream_t stream) {
  (void)in_sizes; (void)n_in; (void)out_size; (void)ws_size;
  const float* z = (const float*)d_in[0];
  const float* trueinp = (const float*)d_in[1];
  const int* tfmask = (const int*)d_in[2];
  const float* fc_w = (const float*)d_in[3];
  const float* fc_b = (const float*)d_in[4];
  const float* ln_w = (const float*)d_in[5];
  const float* ln_b = (const float*)d_in[6];
  const float* w_ih = (const float*)d_in[7];
  const float* b_ih = (const float*)d_in[8];
  const float* w_hh = (const float*)d_in[9];
  const float* b_hh = (const float*)d_in[10];
  float* out = (float*)d_out;

  char* ws = (char*)d_ws;
  size_t o = 0;
  float* xraw = (float*)(ws + o); o += (size_t)2048 * 1024 * 4;
  float* h0f  = (float*)(ws + o); o += (size_t)2048 * 1024 * 4;
  float* gi   = (float*)(ws + o); o += (size_t)2048 * 3072 * 4;
  bf16* h0b   = (bf16*)(ws + o);  o += (size_t)2048 * 1024 * 2;
  bf16* zb    = (bf16*)(ws + o);  o += (size_t)2048 * 256 * 2;
  bf16* fcwb  = (bf16*)(ws + o);  o += (size_t)1024 * 256 * 2;
  bf16* wihb  = (bf16*)(ws + o);  o += (size_t)3072 * 1024 * 2;
  bf16* whhb  = (bf16*)(ws + o);  o += (size_t)3072 * 1024 * 2;
  bf16* whf   = (bf16*)(ws + o);  o += (size_t)3072 * 256 * 2;
  bf16* trueb = (bf16*)(ws + o);  o += (size_t)2048 * TSTEPS * 256 * 2;

  conv_kernel<<<1024, 256, 0, stream>>>(z, (unsigned short*)zb, 2048 * 256 / 4);
  conv_kernel<<<512, 256, 0, stream>>>(fc_w, (unsigned short*)fcwb, 1024 * 256 / 4);
  conv_kernel<<<2048, 256, 0, stream>>>(w_ih, (unsigned short*)wihb, 3072 * 1024 / 4);
  conv_kernel<<<2048, 256, 0, stream>>>(w_hh, (unsigned short*)whhb, 3072 * 1024 / 4);
  conv_kernel<<<2048, 256, 0, stream>>>(trueinp, (unsigned short*)trueb, 2048 * TSTEPS * 256 / 4);
  fold_kernel<<<768, 256, 0, stream>>>(w_hh, (unsigned short*)whf);

  gemm_fc_kernel<<<dim3(16, 16), 256, 0, stream>>>(zb, fcwb, fc_b, xraw);
  ln_kernel<<<2048, 256, 0, stream>>>(xraw, ln_w, ln_b, h0b, h0f);
  gemm_gi_kernel<<<dim3(16, 32), 256, 0, stream>>>(h0b, wihb, b_ih, gi);

  batch_masked_kernel<<<dim3(16, 32, TSTEPS), 256, 0, stream>>>(trueb, trueinp, tfmask, whf,
                                                                b_hh, gi, out);

  const float* prev = h0f;
  for (int t = 0; t < TSTEPS; ++t) {
    step_kernel<<<512, 256, 0, stream>>>(prev, tfmask, whhb, b_hh, gi, out, t);
    prev = out + (size_t)t * 2048 * 1024;
  }
}

// Round 10
// 640.446 us; speedup vs baseline: 1.7922x; 1.1106x over previous
//
#include <hip/hip_runtime.h>
#include <hip/hip_bf16.h>

#define TSTEPS 28

typedef __attribute__((ext_vector_type(8))) short bf16x8;
typedef __attribute__((ext_vector_type(4))) float f32x4;
typedef __attribute__((ext_vector_type(4))) unsigned short u16x4;
typedef __hip_bfloat16 bf16;

__device__ __forceinline__ unsigned short f2b(float f) {
  bf16 h = __float2bfloat16(f);
  return *reinterpret_cast<unsigned short*>(&h);
}
__device__ __forceinline__ float b2f(unsigned short u) {
  bf16 h = *reinterpret_cast<bf16*>(&u);
  return __bfloat162float(h);
}

__device__ __forceinline__ void gload16(const void* g, void* l) {
  __builtin_amdgcn_global_load_lds(
      (const __attribute__((address_space(1))) void*)g,
      (__attribute__((address_space(3))) void*)l, 16, 0, 0);
}

__device__ __forceinline__ float sigm(float x) { return 1.f / (1.f + __expf(-x)); }
__device__ __forceinline__ float tanh_fast(float x) {
  const float e2 = __expf(2.f * x);
  return 1.f - 2.f / (e2 + 1.f);
}

// ---------------- f32 -> bf16 convert (vectorized) ----------------
__global__ void conv_kernel(const float* __restrict__ in, unsigned short* __restrict__ out, int n4) {
  int i = blockIdx.x * blockDim.x + threadIdx.x;
  const int stride = gridDim.x * blockDim.x;
  for (; i < n4; i += stride) {
    const float4 v = *(const float4*)&in[(size_t)i * 4];
    u16x4 o;
    o.x = f2b(v.x); o.y = f2b(v.y); o.z = f2b(v.z); o.w = f2b(v.w);
    *(u16x4*)&out[(size_t)i * 4] = o;
  }
}

// ---------------- fold whh over the 4x tiled K: whf[n][k] = sum_j whh[n][k+256j] ----------------
__global__ __launch_bounds__(256) void fold_kernel(const float* __restrict__ whh,
                                                   unsigned short* __restrict__ whf) {
  const int idx = blockIdx.x * 256 + threadIdx.x;
  const int n = idx >> 6, k4 = (idx & 63) << 2;
  const float* r = &whh[(size_t)n * 1024 + k4];
  const float4 a = *(const float4*)r;
  const float4 b = *(const float4*)(r + 256);
  const float4 c = *(const float4*)(r + 512);
  const float4 d = *(const float4*)(r + 768);
  u16x4 o;
  o.x = f2b(a.x + b.x + c.x + d.x);
  o.y = f2b(a.y + b.y + c.y + d.y);
  o.z = f2b(a.z + b.z + c.z + d.z);
  o.w = f2b(a.w + b.w + c.w + d.w);
  *(u16x4*)&whf[(size_t)n * 256 + k4] = o;
}

// ---------------- fc GEMM: C = A*W^T + bias (f32 out), BM=128 BN=64 BK=32, K=256 ----------------
__global__ __launch_bounds__(256, 2) void gemm_fc_kernel(
    const bf16* __restrict__ A, const bf16* __restrict__ W,
    const float* __restrict__ bias, float* __restrict__ out) {
  constexpr int K = 256, NT = K / 32;
  __shared__ __align__(16) bf16 lds[2][6144];
  const int tid = threadIdx.x;
  const int lane = tid & 63;
  const int l15 = lane & 15, l4 = lane >> 4;
  const int wid = tid >> 6, wm = wid >> 1, wn = wid & 1;
  const int m0 = blockIdx.x * 128, n0 = blockIdx.y * 64;
  const int ra = tid >> 2, cb = (tid & 3) * 8;

  f32x4 acc[4][2] = {};

  auto STAGE = [&](int buf, int kt) {
    const int k0 = kt * 32;
    gload16(&A[(size_t)(m0 + ra) * K + k0 + cb], &lds[buf][tid * 8]);
    gload16(&A[(size_t)(m0 + 64 + ra) * K + k0 + cb], &lds[buf][2048 + tid * 8]);
    gload16(&W[(size_t)(n0 + ra) * K + k0 + cb], &lds[buf][4096 + tid * 8]);
  };

  STAGE(0, 0);
  __syncthreads();
  for (int kt = 0; kt < NT; ++kt) {
    const int buf = kt & 1;
    if (kt + 1 < NT) STAGE(buf ^ 1, kt + 1);
    bf16x8 af[4], bfr[2];
#pragma unroll
    for (int m = 0; m < 4; ++m)
      af[m] = *(const bf16x8*)&lds[buf][(wm * 64 + m * 16 + l15) * 32 + l4 * 8];
#pragma unroll
    for (int n = 0; n < 2; ++n)
      bfr[n] = *(const bf16x8*)&lds[buf][4096 + (wn * 32 + n * 16 + l15) * 32 + l4 * 8];
#pragma unroll
    for (int m = 0; m < 4; ++m)
#pragma unroll
      for (int n = 0; n < 2; ++n)
        acc[m][n] = __builtin_amdgcn_mfma_f32_16x16x32_bf16(af[m], bfr[n], acc[m][n], 0, 0, 0);
    __syncthreads();
  }

#pragma unroll
  for (int m = 0; m < 4; ++m) {
#pragma unroll
    for (int n = 0; n < 2; ++n) {
      const int col = n0 + wn * 32 + n * 16 + l15;
      const int rowb = m0 + wm * 64 + m * 16 + l4 * 4;
      const float bv = bias[col];
#pragma unroll
      for (int r = 0; r < 4; ++r)
        out[(size_t)(rowb + r) * 1024 + col] = acc[m][n][r] + bv;
    }
  }
}

// ---------------- row LayerNorm -> h0b (bf16) + h0f (f32) ----------------
__global__ __launch_bounds__(256) void ln_kernel(const float* __restrict__ x,
                                                 const float* __restrict__ w,
                                                 const float* __restrict__ b,
                                                 bf16* __restrict__ h0b,
                                                 float* __restrict__ h0f) {
  const int row = blockIdx.x, tid = threadIdx.x;
  const float4 v = *(const float4*)&x[(size_t)row * 1024 + tid * 4];
  float vv[4] = {v.x, v.y, v.z, v.w};
  float s = vv[0] + vv[1] + vv[2] + vv[3];
  float sq = vv[0] * vv[0] + vv[1] * vv[1] + vv[2] * vv[2] + vv[3] * vv[3];
#pragma unroll
  for (int off = 32; off; off >>= 1) {
    s += __shfl_down(s, off);
    sq += __shfl_down(sq, off);
  }
  __shared__ float sa[4], sb[4];
  const int lane = tid & 63, wid = tid >> 6;
  if (lane == 0) { sa[wid] = s; sb[wid] = sq; }
  __syncthreads();
  s = sa[0] + sa[1] + sa[2] + sa[3];
  sq = sb[0] + sb[1] + sb[2] + sb[3];
  const float mu = s * (1.f / 1024.f);
  const float var = sq * (1.f / 1024.f) - mu * mu;
  const float rs = rsqrtf(var + 1e-5f);
#pragma unroll
  for (int j = 0; j < 4; ++j) {
    const int c = tid * 4 + j;
    const float xv = (vv[j] - mu) * rs * w[c] + b[c];
    h0b[(size_t)row * 1024 + c] = __float2bfloat16(xv);
    h0f[(size_t)row * 1024 + c] = xv;
  }
}

// ---------------- gi GEMM -> bf16: gib = bf16(h0b @ w_ih^T + b_ih). BM=64, 3x64 B-rows, K=1024 ----------------
__global__ __launch_bounds__(256, 2) void gemm_gi_kernel(
    const bf16* __restrict__ A,      // [2048][1024] bf16
    const bf16* __restrict__ W,      // [3072][1024] bf16
    const float* __restrict__ bias,  // [3072]
    unsigned short* __restrict__ out) {  // [2048][3072] bf16
  __shared__ __align__(16) bf16 lds[2][8192];
  const int tid = threadIdx.x;
  const int lane = tid & 63, l15 = lane & 15, l4 = lane >> 4;
  const int wid = tid >> 6;
  const int n0 = blockIdx.x * 64, m0 = blockIdx.y * 64;

  f32x4 acc[3][4] = {};

  auto STAGE = [&](int buf, int kt) {
    const int k0 = kt * 32;
    gload16(&A[(size_t)(m0 + (tid >> 2)) * 1024 + k0 + (tid & 3) * 8], &lds[buf][tid * 8]);
#pragma unroll
    for (int j = 0; j < 3; ++j) {
      const int c = tid + j * 256;
      const int r = c >> 2, c8 = (c & 3) * 8;
      gload16(&W[(size_t)((r >> 6) * 1024 + n0 + (r & 63)) * 1024 + k0 + c8],
              &lds[buf][2048 + c * 8]);
    }
  };

  STAGE(0, 0);
  __syncthreads();
  for (int kt = 0; kt < 32; ++kt) {
    const int buf = kt & 1;
    if (kt + 1 < 32) STAGE(buf ^ 1, kt + 1);
    bf16x8 af[4], bfr[3];
#pragma unroll
    for (int m = 0; m < 4; ++m)
      af[m] = *(const bf16x8*)&lds[buf][(m * 16 + l15) * 32 + l4 * 8];
#pragma unroll
    for (int g = 0; g < 3; ++g)
      bfr[g] = *(const bf16x8*)&lds[buf][2048 + (g * 64 + wid * 16 + l15) * 32 + l4 * 8];
#pragma unroll
    for (int g = 0; g < 3; ++g)
#pragma unroll
      for (int m = 0; m < 4; ++m)
        acc[g][m] = __builtin_amdgcn_mfma_f32_16x16x32_bf16(af[m], bfr[g], acc[g][m], 0, 0, 0);
    __syncthreads();
  }

  const int col = n0 + wid * 16 + l15;
#pragma unroll
  for (int g = 0; g < 3; ++g) {
    const float bv = bias[g * 1024 + col];
#pragma unroll
    for (int m = 0; m < 4; ++m) {
      const int rowb = m0 + m * 16 + l4 * 4;
#pragma unroll
      for (int r = 0; r < 4; ++r)
        out[(size_t)(rowb + r) * 3072 + g * 1024 + col] = f2b(acc[g][m][r] + bv);
    }
  }
}

// ---------------- batched masked steps: K=256 folded whf; gi bf16; hinv from trueb ----------------
__global__ __launch_bounds__(256, 2) void batch_masked_kernel(
    const bf16* __restrict__ trueb,   // [2048][28][256] bf16
    const int* __restrict__ tfmask,
    const bf16* __restrict__ whf,     // [3072][256] bf16
    const float* __restrict__ bhh,
    const unsigned short* __restrict__ gib,  // [2048][3072] bf16
    float* __restrict__ out) {
  const int t = blockIdx.z;
  if (tfmask[t] == 0) return;
  __shared__ __align__(16) bf16 lds[2][8192];
  const int tid = threadIdx.x;
  const int lane = tid & 63, l15 = lane & 15, l4 = lane >> 4;
  const int wid = tid >> 6;
  const int n0 = blockIdx.x * 64, m0 = blockIdx.y * 64;

  f32x4 acc[3][4] = {};

  auto STAGE = [&](int buf, int kt) {
    const int k0 = kt * 32;
    gload16(&trueb[((size_t)(m0 + (tid >> 2)) * TSTEPS + t) * 256 + k0 + (tid & 3) * 8],
            &lds[buf][tid * 8]);
#pragma unroll
    for (int j = 0; j < 3; ++j) {
      const int c = tid + j * 256;
      const int r = c >> 2, c8 = (c & 3) * 8;
      gload16(&whf[(size_t)((r >> 6) * 1024 + n0 + (r & 63)) * 256 + k0 + c8],
              &lds[buf][2048 + c * 8]);
    }
  };

  STAGE(0, 0);
  __syncthreads();
  for (int kt = 0; kt < 8; ++kt) {
    const int buf = kt & 1;
    if (kt + 1 < 8) STAGE(buf ^ 1, kt + 1);
    bf16x8 af[4], bfr[3];
#pragma unroll
    for (int m = 0; m < 4; ++m)
      af[m] = *(const bf16x8*)&lds[buf][(m * 16 + l15) * 32 + l4 * 8];
#pragma unroll
    for (int g = 0; g < 3; ++g)
      bfr[g] = *(const bf16x8*)&lds[buf][2048 + (g * 64 + wid * 16 + l15) * 32 + l4 * 8];
#pragma unroll
    for (int g = 0; g < 3; ++g)
#pragma unroll
      for (int m = 0; m < 4; ++m)
        acc[g][m] = __builtin_amdgcn_mfma_f32_16x16x32_bf16(af[m], bfr[g], acc[g][m], 0, 0, 0);
    __syncthreads();
  }

  float* outT = out + (size_t)t * 2048 * 1024;
  const int col = n0 + wid * 16 + l15;
  const float br = bhh[col], bz = bhh[col + 1024], bn_ = bhh[col + 2048];
  const unsigned short* tb = (const unsigned short*)trueb;
#pragma unroll
  for (int m = 0; m < 4; ++m) {
    const int rowb = m0 + m * 16 + l4 * 4;
#pragma unroll
    for (int r = 0; r < 4; ++r) {
      const int row = rowb + r;
      const unsigned short* girow = &gib[(size_t)row * 3072];
      const float ir = b2f(girow[col]), iz = b2f(girow[col + 1024]), inn = b2f(girow[col + 2048]);
      const float hr = acc[0][m][r] + br;
      const float hz = acc[1][m][r] + bz;
      const float hn = acc[2][m][r] + bn_;
      const float hinv = b2f(tb[((size_t)row * TSTEPS + t) * 256 + (col & 255)]);
      const float rg = sigm(ir + hr);
      const float ug = sigm(iz + hz);
      const float ng = tanh_fast(inn + rg * hn);
      outT[(size_t)row * 1024 + col] = (1.f - ug) * ng + ug * hinv;
    }
  }
}

// ---------------- sequential unmasked step, dual A path ----------------
// pred masked (or t=0): A = prevf f32 reg-staged. pred unmasked: A = hbfprev bf16 via gload_lds.
// grid 512 linear (XCD-swizzled), 256 threads, 2 blocks/CU. Epilogue writes out[t] f32 + hbfout bf16.
__global__ __launch_bounds__(256, 2) void step_kernel(
    const float* __restrict__ prevf,   // out[t-1] f32 (or h0f at t=0)
    const bf16* __restrict__ hbfprev,  // bf16 h[t-1] (valid iff pred unmasked)
    bf16* __restrict__ hbfout,         // bf16 h[t] destination
    const int* __restrict__ tfmask,
    const bf16* __restrict__ whh,      // [3072][1024] bf16
    const float* __restrict__ bhh,
    const unsigned short* __restrict__ gib,  // [2048][3072] bf16
    float* __restrict__ out, int t) {
  if (tfmask[t] != 0) return;
  const bool predf32 = (t == 0) || (tfmask[t - 1] != 0);
  const int lid = blockIdx.x;
  const int xcd = lid & 7, rest = lid >> 3;
  const int m0 = (rest & 31) * 64;
  const int n0 = ((xcd << 1) | (rest >> 5)) * 64;

  __shared__ __align__(16) bf16 lds[2][8192];  // A 64x32 + B 192x32
  const int tid = threadIdx.x;
  const int lane = tid & 63, l15 = lane & 15, l4 = lane >> 4;
  const int wid = tid >> 6;

  f32x4 acc[3][4] = {};

  auto STAGE = [&](int buf, int kt) {
    const int k0 = kt * 32;
    if (predf32) {
      const float* src = &prevf[(size_t)(m0 + (tid >> 2)) * 1024 + k0 + (tid & 3) * 8];
      const float4 v0 = *(const float4*)src;
      const float4 v1 = *(const float4*)(src + 4);
      bf16x8 sv;
      sv[0] = (short)f2b(v0.x); sv[1] = (short)f2b(v0.y);
      sv[2] = (short)f2b(v0.z); sv[3] = (short)f2b(v0.w);
      sv[4] = (short)f2b(v1.x); sv[5] = (short)f2b(v1.y);
      sv[6] = (short)f2b(v1.z); sv[7] = (short)f2b(v1.w);
      *(bf16x8*)&lds[buf][tid * 8] = sv;
    } else {
      gload16(&hbfprev[(size_t)(m0 + (tid >> 2)) * 1024 + k0 + (tid & 3) * 8],
              &lds[buf][tid * 8]);
    }
#pragma unroll
    for (int j = 0; j < 3; ++j) {
      const int c = tid + j * 256;
      const int r = c >> 2, c8 = (c & 3) * 8;
      gload16(&whh[(size_t)((r >> 6) * 1024 + n0 + (r & 63)) * 1024 + k0 + c8],
              &lds[buf][2048 + c * 8]);
    }
  };

  STAGE(0, 0);
  __syncthreads();
  for (int kt = 0; kt < 32; ++kt) {
    const int buf = kt & 1;
    if (kt + 1 < 32) STAGE(buf ^ 1, kt + 1);
    bf16x8 af[4], bfr[3];
#pragma unroll
    for (int m = 0; m < 4; ++m)
      af[m] = *(const bf16x8*)&lds[buf][(m * 16 + l15) * 32 + l4 * 8];
#pragma unroll
    for (int g = 0; g < 3; ++g)
      bfr[g] = *(const bf16x8*)&lds[buf][2048 + (g * 64 + wid * 16 + l15) * 32 + l4 * 8];
#pragma unroll
    for (int g = 0; g < 3; ++g)
#pragma unroll
      for (int m = 0; m < 4; ++m)
        acc[g][m] = __builtin_amdgcn_mfma_f32_16x16x32_bf16(af[m], bfr[g], acc[g][m], 0, 0, 0);
    __syncthreads();
  }

  float* outT = out + (size_t)t * 2048 * 1024;
  const int col = n0 + wid * 16 + l15;
  const float br = bhh[col], bz = bhh[col + 1024], bn_ = bhh[col + 2048];
#pragma unroll
  for (int m = 0; m < 4; ++m) {
    const int rowb = m0 + m * 16 + l4 * 4;
#pragma unroll
    for (int r = 0; r < 4; ++r) {
      const int row = rowb + r;
      const unsigned short* girow = &gib[(size_t)row * 3072];
      const float ir = b2f(girow[col]), iz = b2f(girow[col + 1024]), inn = b2f(girow[col + 2048]);
      const float hr = acc[0][m][r] + br;
      const float hz = acc[1][m][r] + bz;
      const float hn = acc[2][m][r] + bn_;
      const float hinv = prevf[(size_t)row * 1024 + col];
      const float rg = sigm(ir + hr);
      const float ug = sigm(iz + hz);
      const float ng = tanh_fast(inn + rg * hn);
      const float hnew = (1.f - ug) * ng + ug * hinv;
      outT[(size_t)row * 1024 + col] = hnew;
      hbfout[(size_t)row * 1024 + col] = __float2bfloat16(hnew);
    }
  }
}

extern "C" void kernel_launch(void* const* d_in, const int* in_sizes, int n_in,
                              void* d_out, int out_size, void* d_ws, size_t ws_size,
                              hipStream_t stream) {
  (void)in_sizes; (void)n_in; (void)out_size; (void)ws_size;
  const float* z = (const float*)d_in[0];
  const float* trueinp = (const float*)d_in[1];
  const int* tfmask = (const int*)d_in[2];
  const float* fc_w = (const float*)d_in[3];
  const float* fc_b = (const float*)d_in[4];
  const float* ln_w = (const float*)d_in[5];
  const float* ln_b = (const float*)d_in[6];
  const float* w_ih = (const float*)d_in[7];
  const float* b_ih = (const float*)d_in[8];
  const float* w_hh = (const float*)d_in[9];
  const float* b_hh = (const float*)d_in[10];
  float* out = (float*)d_out;

  char* ws = (char*)d_ws;
  size_t o = 0;
  float* xraw = (float*)(ws + o); o += (size_t)2048 * 1024 * 4;
  float* h0f  = (float*)(ws + o); o += (size_t)2048 * 1024 * 4;
  unsigned short* gib = (unsigned short*)(ws + o); o += (size_t)2048 * 3072 * 2;
  bf16* h0b   = (bf16*)(ws + o);  o += (size_t)2048 * 1024 * 2;
  bf16* hbf0  = (bf16*)(ws + o);  o += (size_t)2048 * 1024 * 2;
  bf16* hbf1  = (bf16*)(ws + o);  o += (size_t)2048 * 1024 * 2;
  bf16* zb    = (bf16*)(ws + o);  o += (size_t)2048 * 256 * 2;
  bf16* fcwb  = (bf16*)(ws + o);  o += (size_t)1024 * 256 * 2;
  bf16* wihb  = (bf16*)(ws + o);  o += (size_t)3072 * 1024 * 2;
  bf16* whhb  = (bf16*)(ws + o);  o += (size_t)3072 * 1024 * 2;
  bf16* whf   = (bf16*)(ws + o);  o += (size_t)3072 * 256 * 2;
  bf16* trueb = (bf16*)(ws + o);  o += (size_t)2048 * TSTEPS * 256 * 2;

  conv_kernel<<<1024, 256, 0, stream>>>(z, (unsigned short*)zb, 2048 * 256 / 4);
  conv_kernel<<<512, 256, 0, stream>>>(fc_w, (unsigned short*)fcwb, 1024 * 256 / 4);
  conv_kernel<<<2048, 256, 0, stream>>>(w_ih, (unsigned short*)wihb, 3072 * 1024 / 4);
  conv_kernel<<<2048, 256, 0, stream>>>(w_hh, (unsigned short*)whhb, 3072 * 1024 / 4);
  conv_kernel<<<2048, 256, 0, stream>>>(trueinp, (unsigned short*)trueb, 2048 * TSTEPS * 256 / 4);
  fold_kernel<<<768, 256, 0, stream>>>(w_hh, (unsigned short*)whf);

  gemm_fc_kernel<<<dim3(16, 16), 256, 0, stream>>>(zb, fcwb, fc_b, xraw);
  ln_kernel<<<2048, 256, 0, stream>>>(xraw, ln_w, ln_b, h0b, h0f);
  gemm_gi_kernel<<<dim3(16, 32), 256, 0, stream>>>(h0b, wihb, b_ih, gib);

  batch_masked_kernel<<<dim3(16, 32, TSTEPS), 256, 0, stream>>>(trueb, tfmask, whf,
                                                                b_hh, gib, out);

  const float* prev = h0f;
  for (int t = 0; t < TSTEPS; ++t) {
    bf16* hw = (t & 1) ? hbf1 : hbf0;
    const bf16* hr = (t & 1) ? hbf0 : hbf1;
    step_kernel<<<512, 256, 0, stream>>>(prev, hr, hw, tfmask, whhb, b_hh, gib, out, t);
    prev = out + (size_t)t * 2048 * 1024;
  }
}

// Round 12
// 589.043 us; speedup vs baseline: 1.9486x; 1.0873x over previous
//
#include <hip/hip_runtime.h>
#include <hip/hip_bf16.h>

#define TSTEPS 28

typedef __attribute__((ext_vector_type(8))) short bf16x8;
typedef __attribute__((ext_vector_type(4))) float f32x4;
typedef __attribute__((ext_vector_type(4))) unsigned short u16x4;
typedef __hip_bfloat16 bf16;

__device__ __forceinline__ unsigned short f2b(float f) {
  bf16 h = __float2bfloat16(f);
  return *reinterpret_cast<unsigned short*>(&h);
}
__device__ __forceinline__ float b2f(unsigned short u) {
  bf16 h = *reinterpret_cast<bf16*>(&u);
  return __bfloat162float(h);
}

__device__ __forceinline__ void gload16(const void* g, void* l) {
  __builtin_amdgcn_global_load_lds(
      (const __attribute__((address_space(1))) void*)g,
      (__attribute__((address_space(3))) void*)l, 16, 0, 0);
}

__device__ __forceinline__ float sigm(float x) { return 1.f / (1.f + __expf(-x)); }
__device__ __forceinline__ float tanh_fast(float x) {
  const float e2 = __expf(2.f * x);
  return 1.f - 2.f / (e2 + 1.f);
}

// ---------------- f32 -> bf16 convert (vectorized) ----------------
__global__ void conv_kernel(const float* __restrict__ in, unsigned short* __restrict__ out, int n4) {
  int i = blockIdx.x * blockDim.x + threadIdx.x;
  const int stride = gridDim.x * blockDim.x;
  for (; i < n4; i += stride) {
    const float4 v = *(const float4*)&in[(size_t)i * 4];
    u16x4 o;
    o.x = f2b(v.x); o.y = f2b(v.y); o.z = f2b(v.z); o.w = f2b(v.w);
    *(u16x4*)&out[(size_t)i * 4] = o;
  }
}

// ---------------- fold whh over the 4x tiled K: whf[n][k] = sum_j whh[n][k+256j] ----------------
__global__ __launch_bounds__(256) void fold_kernel(const float* __restrict__ whh,
                                                   unsigned short* __restrict__ whf) {
  const int idx = blockIdx.x * 256 + threadIdx.x;
  const int n = idx >> 6, k4 = (idx & 63) << 2;
  const float* r = &whh[(size_t)n * 1024 + k4];
  const float4 a = *(const float4*)r;
  const float4 b = *(const float4*)(r + 256);
  const float4 c = *(const float4*)(r + 512);
  const float4 d = *(const float4*)(r + 768);
  u16x4 o;
  o.x = f2b(a.x + b.x + c.x + d.x);
  o.y = f2b(a.y + b.y + c.y + d.y);
  o.z = f2b(a.z + b.z + c.z + d.z);
  o.w = f2b(a.w + b.w + c.w + d.w);
  *(u16x4*)&whf[(size_t)n * 256 + k4] = o;
}

// ---------------- fc GEMM: C = A*W^T + bias (f32 out), BM=128 BN=64 BK=32, K=256 ----------------
__global__ __launch_bounds__(256, 2) void gemm_fc_kernel(
    const bf16* __restrict__ A, const bf16* __restrict__ W,
    const float* __restrict__ bias, float* __restrict__ out) {
  constexpr int K = 256, NT = K / 32;
  __shared__ __align__(16) bf16 lds[2][6144];
  const int tid = threadIdx.x;
  const int lane = tid & 63;
  const int l15 = lane & 15, l4 = lane >> 4;
  const int wid = tid >> 6, wm = wid >> 1, wn = wid & 1;
  const int m0 = blockIdx.x * 128, n0 = blockIdx.y * 64;
  const int ra = tid >> 2, cb = (tid & 3) * 8;

  f32x4 acc[4][2] = {};

  auto STAGE = [&](int buf, int kt) {
    const int k0 = kt * 32;
    gload16(&A[(size_t)(m0 + ra) * K + k0 + cb], &lds[buf][tid * 8]);
    gload16(&A[(size_t)(m0 + 64 + ra) * K + k0 + cb], &lds[buf][2048 + tid * 8]);
    gload16(&W[(size_t)(n0 + ra) * K + k0 + cb], &lds[buf][4096 + tid * 8]);
  };

  STAGE(0, 0);
  __syncthreads();
  for (int kt = 0; kt < NT; ++kt) {
    const int buf = kt & 1;
    if (kt + 1 < NT) STAGE(buf ^ 1, kt + 1);
    bf16x8 af[4], bfr[2];
#pragma unroll
    for (int m = 0; m < 4; ++m)
      af[m] = *(const bf16x8*)&lds[buf][(wm * 64 + m * 16 + l15) * 32 + l4 * 8];
#pragma unroll
    for (int n = 0; n < 2; ++n)
      bfr[n] = *(const bf16x8*)&lds[buf][4096 + (wn * 32 + n * 16 + l15) * 32 + l4 * 8];
#pragma unroll
    for (int m = 0; m < 4; ++m)
#pragma unroll
      for (int n = 0; n < 2; ++n)
        acc[m][n] = __builtin_amdgcn_mfma_f32_16x16x32_bf16(af[m], bfr[n], acc[m][n], 0, 0, 0);
    __syncthreads();
  }

#pragma unroll
  for (int m = 0; m < 4; ++m) {
#pragma unroll
    for (int n = 0; n < 2; ++n) {
      const int col = n0 + wn * 32 + n * 16 + l15;
      const int rowb = m0 + wm * 64 + m * 16 + l4 * 4;
      const float bv = bias[col];
#pragma unroll
      for (int r = 0; r < 4; ++r)
        out[(size_t)(rowb + r) * 1024 + col] = acc[m][n][r] + bv;
    }
  }
}

// ---------------- row LayerNorm -> h0b (bf16) + h0f (f32) ----------------
__global__ __launch_bounds__(256) void ln_kernel(const float* __restrict__ x,
                                                 const float* __restrict__ w,
                                                 const float* __restrict__ b,
                                                 bf16* __restrict__ h0b,
                                                 float* __restrict__ h0f) {
  const int row = blockIdx.x, tid = threadIdx.x;
  const float4 v = *(const float4*)&x[(size_t)row * 1024 + tid * 4];
  float vv[4] = {v.x, v.y, v.z, v.w};
  float s = vv[0] + vv[1] + vv[2] + vv[3];
  float sq = vv[0] * vv[0] + vv[1] * vv[1] + vv[2] * vv[2] + vv[3] * vv[3];
#pragma unroll
  for (int off = 32; off; off >>= 1) {
    s += __shfl_down(s, off);
    sq += __shfl_down(sq, off);
  }
  __shared__ float sa[4], sb[4];
  const int lane = tid & 63, wid = tid >> 6;
  if (lane == 0) { sa[wid] = s; sb[wid] = sq; }
  __syncthreads();
  s = sa[0] + sa[1] + sa[2] + sa[3];
  sq = sb[0] + sb[1] + sb[2] + sb[3];
  const float mu = s * (1.f / 1024.f);
  const float var = sq * (1.f / 1024.f) - mu * mu;
  const float rs = rsqrtf(var + 1e-5f);
#pragma unroll
  for (int j = 0; j < 4; ++j) {
    const int c = tid * 4 + j;
    const float xv = (vv[j] - mu) * rs * w[c] + b[c];
    h0b[(size_t)row * 1024 + c] = __float2bfloat16(xv);
    h0f[(size_t)row * 1024 + c] = xv;
  }
}

// ---------------- gi GEMM -> bf16. BM=64, 3x64 B-rows, BK=64 XOR-swizzled, K=1024 ----------------
// Swizzle (Rule 21): LDS dest linear (gload_lds requirement); global source column pre-swizzled
// kk=(chunk^row)&7; read applies the same XOR -> ds_read_b128 spreads 8 ways (conflict-free-ish).
__global__ __launch_bounds__(256, 2) void gemm_gi_kernel(
    const bf16* __restrict__ A,      // [2048][1024] bf16
    const bf16* __restrict__ W,      // [3072][1024] bf16
    const float* __restrict__ bias,  // [3072]
    unsigned short* __restrict__ out) {  // [2048][3072] bf16
  __shared__ __align__(16) bf16 lds[2][16384];  // A 64x64 + B 192x64
  const int tid = threadIdx.x;
  const int lane = tid & 63, l15 = lane & 15, l4 = lane >> 4;
  const int wid = tid >> 6;
  const int n0 = blockIdx.x * 64, m0 = blockIdx.y * 64;

  f32x4 acc[3][4] = {};

  auto STAGE = [&](int buf, int kt) {
    const int k0 = kt * 64;
#pragma unroll
    for (int j = 0; j < 2; ++j) {
      const int c = tid + j * 256;
      const int row = c >> 3, kk = ((c & 7) ^ (row & 7)) * 8;
      gload16(&A[(size_t)(m0 + row) * 1024 + k0 + kk], &lds[buf][c * 8]);
    }
#pragma unroll
    for (int j = 0; j < 6; ++j) {
      const int c = tid + j * 256;
      const int row = c >> 3, kk = ((c & 7) ^ (row & 7)) * 8;
      gload16(&W[(size_t)((row >> 6) * 1024 + n0 + (row & 63)) * 1024 + k0 + kk],
              &lds[buf][4096 + c * 8]);
    }
  };

  STAGE(0, 0);
  __syncthreads();
  for (int kt = 0; kt < 16; ++kt) {
    const int buf = kt & 1;
    if (kt + 1 < 16) STAGE(buf ^ 1, kt + 1);
#pragma unroll
    for (int ks = 0; ks < 2; ++ks) {
      const int x = (((ks << 2) | l4) ^ (l15 & 7)) * 8;
      bf16x8 af[4], bfr[3];
#pragma unroll
      for (int m = 0; m < 4; ++m)
        af[m] = *(const bf16x8*)&lds[buf][(m * 16 + l15) * 64 + x];
#pragma unroll
      for (int g = 0; g < 3; ++g)
        bfr[g] = *(const bf16x8*)&lds[buf][4096 + (g * 64 + wid * 16 + l15) * 64 + x];
#pragma unroll
      for (int g = 0; g < 3; ++g)
#pragma unroll
        for (int m = 0; m < 4; ++m)
          acc[g][m] = __builtin_amdgcn_mfma_f32_16x16x32_bf16(af[m], bfr[g], acc[g][m], 0, 0, 0);
    }
    __syncthreads();
  }

  const int col = n0 + wid * 16 + l15;
#pragma unroll
  for (int g = 0; g < 3; ++g) {
    const float bv = bias[g * 1024 + col];
#pragma unroll
    for (int m = 0; m < 4; ++m) {
      const int rowb = m0 + m * 16 + l4 * 4;
#pragma unroll
      for (int r = 0; r < 4; ++r)
        out[(size_t)(rowb + r) * 3072 + g * 1024 + col] = f2b(acc[g][m][r] + bv);
    }
  }
}

// ---------------- batched masked steps: K=256 folded whf, BK=64 swizzled ----------------
__global__ __launch_bounds__(256, 2) void batch_masked_kernel(
    const bf16* __restrict__ trueb,   // [2048][28][256] bf16
    const int* __restrict__ tfmask,
    const bf16* __restrict__ whf,     // [3072][256] bf16
    const float* __restrict__ bhh,
    const unsigned short* __restrict__ gib,  // [2048][3072] bf16
    float* __restrict__ out) {
  const int t = blockIdx.z;
  if (tfmask[t] == 0) return;
  __shared__ __align__(16) bf16 lds[2][16384];
  const int tid = threadIdx.x;
  const int lane = tid & 63, l15 = lane & 15, l4 = lane >> 4;
  const int wid = tid >> 6;
  const int n0 = blockIdx.x * 64, m0 = blockIdx.y * 64;

  f32x4 acc[3][4] = {};

  auto STAGE = [&](int buf, int kt) {
    const int k0 = kt * 64;
#pragma unroll
    for (int j = 0; j < 2; ++j) {
      const int c = tid + j * 256;
      const int row = c >> 3, kk = ((c & 7) ^ (row & 7)) * 8;
      gload16(&trueb[((size_t)(m0 + row) * TSTEPS + t) * 256 + k0 + kk], &lds[buf][c * 8]);
    }
#pragma unroll
    for (int j = 0; j < 6; ++j) {
      const int c = tid + j * 256;
      const int row = c >> 3, kk = ((c & 7) ^ (row & 7)) * 8;
      gload16(&whf[(size_t)((row >> 6) * 1024 + n0 + (row & 63)) * 256 + k0 + kk],
              &lds[buf][4096 + c * 8]);
    }
  };

  STAGE(0, 0);
  __syncthreads();
  for (int kt = 0; kt < 4; ++kt) {
    const int buf = kt & 1;
    if (kt + 1 < 4) STAGE(buf ^ 1, kt + 1);
#pragma unroll
    for (int ks = 0; ks < 2; ++ks) {
      const int x = (((ks << 2) | l4) ^ (l15 & 7)) * 8;
      bf16x8 af[4], bfr[3];
#pragma unroll
      for (int m = 0; m < 4; ++m)
        af[m] = *(const bf16x8*)&lds[buf][(m * 16 + l15) * 64 + x];
#pragma unroll
      for (int g = 0; g < 3; ++g)
        bfr[g] = *(const bf16x8*)&lds[buf][4096 + (g * 64 + wid * 16 + l15) * 64 + x];
#pragma unroll
      for (int g = 0; g < 3; ++g)
#pragma unroll
        for (int m = 0; m < 4; ++m)
          acc[g][m] = __builtin_amdgcn_mfma_f32_16x16x32_bf16(af[m], bfr[g], acc[g][m], 0, 0, 0);
    }
    __syncthreads();
  }

  float* outT = out + (size_t)t * 2048 * 1024;
  const int col = n0 + wid * 16 + l15;
  const float br = bhh[col], bz = bhh[col + 1024], bn_ = bhh[col + 2048];
  const unsigned short* tb = (const unsigned short*)trueb;
#pragma unroll
  for (int m = 0; m < 4; ++m) {
    const int rowb = m0 + m * 16 + l4 * 4;
#pragma unroll
    for (int r = 0; r < 4; ++r) {
      const int row = rowb + r;
      const unsigned short* girow = &gib[(size_t)row * 3072];
      const float ir = b2f(girow[col]), iz = b2f(girow[col + 1024]), inn = b2f(girow[col + 2048]);
      const float hr = acc[0][m][r] + br;
      const float hz = acc[1][m][r] + bz;
      const float hn = acc[2][m][r] + bn_;
      const float hinv = b2f(tb[((size_t)row * TSTEPS + t) * 256 + (col & 255)]);
      const float rg = sigm(ir + hr);
      const float ug = sigm(iz + hz);
      const float ng = tanh_fast(inn + rg * hn);
      outT[(size_t)row * 1024 + col] = (1.f - ug) * ng + ug * hinv;
    }
  }
}

// ---------------- sequential unmasked step, BK=64 swizzled, dual A path ----------------
// grid 512 linear (XCD-swizzled), 256 threads, 2 blocks/CU (64KB LDS).
__global__ __launch_bounds__(256, 2) void step_kernel(
    const float* __restrict__ prevf,   // out[t-1] f32 (or h0f at t=0)
    const bf16* __restrict__ hbfprev,  // bf16 h[t-1] (valid iff pred unmasked)
    bf16* __restrict__ hbfout,         // bf16 h[t] destination
    const int* __restrict__ tfmask,
    const bf16* __restrict__ whh,      // [3072][1024] bf16
    const float* __restrict__ bhh,
    const unsigned short* __restrict__ gib,  // [2048][3072] bf16
    float* __restrict__ out, int t) {
  if (tfmask[t] != 0) return;
  const bool predf32 = (t == 0) || (tfmask[t - 1] != 0);
  const int lid = blockIdx.x;
  const int xcd = lid & 7, rest = lid >> 3;
  const int m0 = (rest & 31) * 64;
  const int n0 = ((xcd << 1) | (rest >> 5)) * 64;

  __shared__ __align__(16) bf16 lds[2][16384];  // A 64x64 + B 192x64
  const int tid = threadIdx.x;
  const int lane = tid & 63, l15 = lane & 15, l4 = lane >> 4;
  const int wid = tid >> 6;

  f32x4 acc[3][4] = {};

  auto STAGE = [&](int buf, int kt) {
    const int k0 = kt * 64;
#pragma unroll
    for (int j = 0; j < 2; ++j) {
      const int c = tid + j * 256;
      const int row = c >> 3, kk = ((c & 7) ^ (row & 7)) * 8;
      if (predf32) {
        const float* src = &prevf[(size_t)(m0 + row) * 1024 + k0 + kk];
        const float4 v0 = *(const float4*)src;
        const float4 v1 = *(const float4*)(src + 4);
        bf16x8 sv;
        sv[0] = (short)f2b(v0.x); sv[1] = (short)f2b(v0.y);
        sv[2] = (short)f2b(v0.z); sv[3] = (short)f2b(v0.w);
        sv[4] = (short)f2b(v1.x); sv[5] = (short)f2b(v1.y);
        sv[6] = (short)f2b(v1.z); sv[7] = (short)f2b(v1.w);
        *(bf16x8*)&lds[buf][c * 8] = sv;
      } else {
        gload16(&hbfprev[(size_t)(m0 + row) * 1024 + k0 + kk], &lds[buf][c * 8]);
      }
    }
#pragma unroll
    for (int j = 0; j < 6; ++j) {
      const int c = tid + j * 256;
      const int row = c >> 3, kk = ((c & 7) ^ (row & 7)) * 8;
      gload16(&whh[(size_t)((row >> 6) * 1024 + n0 + (row & 63)) * 1024 + k0 + kk],
              &lds[buf][4096 + c * 8]);
    }
  };

  STAGE(0, 0);
  __syncthreads();
  for (int kt = 0; kt < 16; ++kt) {
    const int buf = kt & 1;
    if (kt + 1 < 16) STAGE(buf ^ 1, kt + 1);
#pragma unroll
    for (int ks = 0; ks < 2; ++ks) {
      const int x = (((ks << 2) | l4) ^ (l15 & 7)) * 8;
      bf16x8 af[4], bfr[3];
#pragma unroll
      for (int m = 0; m < 4; ++m)
        af[m] = *(const bf16x8*)&lds[buf][(m * 16 + l15) * 64 + x];
#pragma unroll
      for (int g = 0; g < 3; ++g)
        bfr[g] = *(const bf16x8*)&lds[buf][4096 + (g * 64 + wid * 16 + l15) * 64 + x];
#pragma unroll
      for (int g = 0; g < 3; ++g)
#pragma unroll
        for (int m = 0; m < 4; ++m)
          acc[g][m] = __builtin_amdgcn_mfma_f32_16x16x32_bf16(af[m], bfr[g], acc[g][m], 0, 0, 0);
    }
    __syncthreads();
  }

  float* outT = out + (size_t)t * 2048 * 1024;
  const int col = n0 + wid * 16 + l15;
  const float br = bhh[col], bz = bhh[col + 1024], bn_ = bhh[col + 2048];
#pragma unroll
  for (int m = 0; m < 4; ++m) {
    const int rowb = m0 + m * 16 + l4 * 4;
#pragma unroll
    for (int r = 0; r < 4; ++r) {
      const int row = rowb + r;
      const unsigned short* girow = &gib[(size_t)row * 3072];
      const float ir = b2f(girow[col]), iz = b2f(girow[col + 1024]), inn = b2f(girow[col + 2048]);
      const float hr = acc[0][m][r] + br;
      const float hz = acc[1][m][r] + bz;
      const float hn = acc[2][m][r] + bn_;
      const float hinv = prevf[(size_t)row * 1024 + col];
      const float rg = sigm(ir + hr);
      const float ug = sigm(iz + hz);
      const float ng = tanh_fast(inn + rg * hn);
      const float hnew = (1.f - ug) * ng + ug * hinv;
      outT[(size_t)row * 1024 + col] = hnew;
      hbfout[(size_t)row * 1024 + col] = __float2bfloat16(hnew);
    }
  }
}

extern "C" void kernel_launch(void* const* d_in, const int* in_sizes, int n_in,
                              void* d_out, int out_size, void* d_ws, size_t ws_size,
                              hipStream_t stream) {
  (void)in_sizes; (void)n_in; (void)out_size; (void)ws_size;
  const float* z = (const float*)d_in[0];
  const float* trueinp = (const float*)d_in[1];
  const int* tfmask = (const int*)d_in[2];
  const float* fc_w = (const float*)d_in[3];
  const float* fc_b = (const float*)d_in[4];
  const float* ln_w = (const float*)d_in[5];
  const float* ln_b = (const float*)d_in[6];
  const float* w_ih = (const float*)d_in[7];
  const float* b_ih = (const float*)d_in[8];
  const float* w_hh = (const float*)d_in[9];
  const float* b_hh = (const float*)d_in[10];
  float* out = (float*)d_out;

  char* ws = (char*)d_ws;
  size_t o = 0;
  float* xraw = (float*)(ws + o); o += (size_t)2048 * 1024 * 4;
  float* h0f  = (float*)(ws + o); o += (size_t)2048 * 1024 * 4;
  unsigned short* gib = (unsigned short*)(ws + o); o += (size_t)2048 * 3072 * 2;
  bf16* h0b   = (bf16*)(ws + o);  o += (size_t)2048 * 1024 * 2;
  bf16* hbf0  = (bf16*)(ws + o);  o += (size_t)2048 * 1024 * 2;
  bf16* hbf1  = (bf16*)(ws + o);  o += (size_t)2048 * 1024 * 2;
  bf16* zb    = (bf16*)(ws + o);  o += (size_t)2048 * 256 * 2;
  bf16* fcwb  = (bf16*)(ws + o);  o += (size_t)1024 * 256 * 2;
  bf16* wihb  = (bf16*)(ws + o);  o += (size_t)3072 * 1024 * 2;
  bf16* whhb  = (bf16*)(ws + o);  o += (size_t)3072 * 1024 * 2;
  bf16* whf   = (bf16*)(ws + o);  o += (size_t)3072 * 256 * 2;
  bf16* trueb = (bf16*)(ws + o);  o += (size_t)2048 * TSTEPS * 256 * 2;

  conv_kernel<<<1024, 256, 0, stream>>>(z, (unsigned short*)zb, 2048 * 256 / 4);
  conv_kernel<<<512, 256, 0, stream>>>(fc_w, (unsigned short*)fcwb, 1024 * 256 / 4);
  conv_kernel<<<2048, 256, 0, stream>>>(w_ih, (unsigned short*)wihb, 3072 * 1024 / 4);
  conv_kernel<<<2048, 256, 0, stream>>>(w_hh, (unsigned short*)whhb, 3072 * 1024 / 4);
  conv_kernel<<<2048, 256, 0, stream>>>(trueinp, (unsigned short*)trueb, 2048 * TSTEPS * 256 / 4);
  fold_kernel<<<768, 256, 0, stream>>>(w_hh, (unsigned short*)whf);

  gemm_fc_kernel<<<dim3(16, 16), 256, 0, stream>>>(zb, fcwb, fc_b, xraw);
  ln_kernel<<<2048, 256, 0, stream>>>(xraw, ln_w, ln_b, h0b, h0f);
  gemm_gi_kernel<<<dim3(16, 32), 256, 0, stream>>>(h0b, wihb, b_ih, gib);

  batch_masked_kernel<<<dim3(16, 32, TSTEPS), 256, 0, stream>>>(trueb, tfmask, whf,
                                                                b_hh, gib, out);

  const float* prev = h0f;
  for (int t = 0; t < TSTEPS; ++t) {
    bf16* hw = (t & 1) ? hbf1 : hbf0;
    const bf16* hr = (t & 1) ? hbf0 : hbf1;
    step_kernel<<<512, 256, 0, stream>>>(prev, hr, hw, tfmask, whhb, b_hh, gib, out, t);
    prev = out + (size_t)t * 2048 * 1024;
  }
}